// Round 1
// baseline (4383.534 us; speedup 1.0000x reference)
//
#include <hip/hip_runtime.h>
#include <hip/hip_bf16.h>

// AttentionCircuit: x -> (h_qk,h_v) -> (Q,K,V) -> causal flash attention -> @W_O^T
// Round 1: correctness-first, fp32 vector compute, tiled LDS GEMMs, flash attention.
// Q/K kept fp32 (score precision through exp); V/attn_out bf16 (linear paths).

namespace {
constexpr int kS  = 2048;
constexpr int kD  = 1024;
constexpr int kR  = 64;
constexpr int kN  = 32;    // neurons per bank
}

typedef unsigned short u16;

__device__ __forceinline__ u16 f2bf_bits(float f) {
  union { float f; unsigned u; } cv; cv.f = f;
  unsigned u = cv.u;
  unsigned r = u + 0x7fffu + ((u >> 16) & 1u);   // round-to-nearest-even
  return (u16)(r >> 16);
}
__device__ __forceinline__ float bf2f(u16 b) {
  union { unsigned u; float f; } cv; cv.u = ((unsigned)b) << 16; return cv.f;
}
__device__ __forceinline__ float dot4(float4 a, float4 b) {
  return a.x*b.x + a.y*b.y + a.z*b.z + a.w*b.w;
}

__global__ __launch_bounds__(256) void zero_f32(float* __restrict__ p) {
  int idx = blockIdx.x * 256 + threadIdx.x;
  float4 z = {0.f, 0.f, 0.f, 0.f};
  reinterpret_cast<float4*>(p)[idx] = z;
}

// ---------------------------------------------------------------------------
// K1: h_qk[t,r] = sum_n fqk_w[t,n] * sum_d x[t,d]*f[n,d,r]   (n in 0..31)
//     h_v [t,r] = sum_n fv_w [t,n] * sum_d x[t,d]*f[32+n,d,r]
// grid (128 token-tiles, 8 n-chunks of 8); chunks 0..3 -> qk, 4..7 -> v.
// Partial sums atomically added into zero-initialized h buffers.
// ---------------------------------------------------------------------------
__global__ __launch_bounds__(256) void h_kernel(
    const float* __restrict__ x,
    const float* __restrict__ fqk_w,
    const float* __restrict__ fv_w,
    const float* __restrict__ f_neurons,
    float* __restrict__ h_qk,
    float* __restrict__ h_v)
{
  __shared__ float xs[16][65];   // [k][token], transposed, pad 65
  __shared__ float fs[16][64];   // [k][r]
  const int tid = threadIdx.x;
  const int tx = tid & 15, ty = tid >> 4;
  const int ty4 = ty * 4, tx4 = tx * 4;
  const int tok0 = blockIdx.x * 64;
  const int chunk = blockIdx.y;            // 0..7
  const bool is_qk = (chunk < 4);
  const int n_base = chunk * 8;            // global n into f_neurons (0..56)
  const float* __restrict__ wptr = is_qk ? fqk_w : fv_w;
  const int nl = is_qk ? n_base : (n_base - 32);

  float acct[4][4] = {};

  for (int d0 = 0; d0 < kD; d0 += 16) {
    {
      int idx = tid;
#pragma unroll
      for (int e = 0; e < 4; ++e, idx += 256) {
        int i = idx >> 4, k = idx & 15;
        xs[k][i] = x[(size_t)(tok0 + i) * kD + d0 + k];
      }
    }
#pragma unroll 1
    for (int m = 0; m < 8; ++m) {
      const float* __restrict__ fp =
          f_neurons + ((size_t)(n_base + m) * kD + d0) * kR;
      {
        int k = tid >> 4, r4 = (tid & 15) * 4;
        *reinterpret_cast<float4*>(&fs[k][r4]) =
            *reinterpret_cast<const float4*>(&fp[k * kR + r4]);
      }
      const float w0 = wptr[(size_t)(tok0 + ty4 + 0) * kN + nl + m];
      const float w1 = wptr[(size_t)(tok0 + ty4 + 1) * kN + nl + m];
      const float w2 = wptr[(size_t)(tok0 + ty4 + 2) * kN + nl + m];
      const float w3 = wptr[(size_t)(tok0 + ty4 + 3) * kN + nl + m];
      __syncthreads();
#pragma unroll
      for (int k = 0; k < 16; ++k) {
        const float4 b4 = *reinterpret_cast<const float4*>(&fs[k][tx4]);
        const float a0 = xs[k][ty4 + 0] * w0;
        const float a1 = xs[k][ty4 + 1] * w1;
        const float a2 = xs[k][ty4 + 2] * w2;
        const float a3 = xs[k][ty4 + 3] * w3;
        acct[0][0] += a0*b4.x; acct[0][1] += a0*b4.y; acct[0][2] += a0*b4.z; acct[0][3] += a0*b4.w;
        acct[1][0] += a1*b4.x; acct[1][1] += a1*b4.y; acct[1][2] += a1*b4.z; acct[1][3] += a1*b4.w;
        acct[2][0] += a2*b4.x; acct[2][1] += a2*b4.y; acct[2][2] += a2*b4.z; acct[2][3] += a2*b4.w;
        acct[3][0] += a3*b4.x; acct[3][1] += a3*b4.y; acct[3][2] += a3*b4.z; acct[3][3] += a3*b4.w;
      }
      __syncthreads();
    }
  }
  float* __restrict__ hout = is_qk ? h_qk : h_v;
#pragma unroll
  for (int i = 0; i < 4; ++i)
#pragma unroll
    for (int j = 0; j < 4; ++j)
      atomicAdd(&hout[(size_t)(tok0 + ty4 + i) * kR + tx4 + j], acct[i][j]);
}

// ---------------------------------------------------------------------------
// K2: C[t,d] = sum_{n,r} w[t,n]*h[t,r]*r_neurons[bank+n, r, d]
// which: 0 -> Q (fp32), 1 -> K (fp32), 2 -> V (bf16). Tile 64 tok x 128 d.
// A-operand synthesized from LDS h-tile * per-n token weights.
// ---------------------------------------------------------------------------
__global__ __launch_bounds__(256) void qkv_kernel(
    const float* __restrict__ h_qk,
    const float* __restrict__ h_v,
    const float* __restrict__ wq,
    const float* __restrict__ wk,
    const float* __restrict__ wv,
    const float* __restrict__ r_neurons,
    float* __restrict__ Qf,
    float* __restrict__ Kf,
    u16* __restrict__ Vb)
{
  __shared__ float hs[64][65];
  __shared__ float Bs[16][128];
  const int tid = threadIdx.x;
  const int tx = tid & 15, ty = tid >> 4;
  const int ty4 = ty * 4, tx8 = tx * 8;
  const int dT = blockIdx.x * 128;
  const int tok0 = blockIdx.y * 64;
  const int which = blockIdx.z;
  const float* __restrict__ h = (which == 2) ? h_v : h_qk;
  const float* __restrict__ w = (which == 0) ? wq : (which == 1) ? wk : wv;
  const int bank = (which == 2) ? 32 : 0;

  {
    int idx = tid;
#pragma unroll
    for (int e = 0; e < 16; ++e, idx += 256) {
      int i = idx >> 6, r = idx & 63;
      hs[i][r] = h[(size_t)(tok0 + i) * kR + r];
    }
  }

  float acc[4][8] = {};

#pragma unroll 1
  for (int n = 0; n < kN; ++n) {
    const float* __restrict__ bp =
        r_neurons + (size_t)(bank + n) * (kR * kD) + dT;
    const float w0 = w[(size_t)(tok0 + ty4 + 0) * kN + n];
    const float w1 = w[(size_t)(tok0 + ty4 + 1) * kN + n];
    const float w2 = w[(size_t)(tok0 + ty4 + 2) * kN + n];
    const float w3 = w[(size_t)(tok0 + ty4 + 3) * kN + n];
#pragma unroll 1
    for (int r0 = 0; r0 < kR; r0 += 16) {
      {
        int idx = tid;
#pragma unroll
        for (int e = 0; e < 2; ++e, idx += 256) {
          int rr = idx >> 5, c4 = (idx & 31) * 4;
          *reinterpret_cast<float4*>(&Bs[rr][c4]) =
              *reinterpret_cast<const float4*>(&bp[(size_t)(r0 + rr) * kD + c4]);
        }
      }
      __syncthreads();
#pragma unroll
      for (int k = 0; k < 16; ++k) {
        const int r = r0 + k;
        const float a0 = hs[ty4 + 0][r] * w0;
        const float a1 = hs[ty4 + 1][r] * w1;
        const float a2 = hs[ty4 + 2][r] * w2;
        const float a3 = hs[ty4 + 3][r] * w3;
        const float4 bA = *reinterpret_cast<const float4*>(&Bs[k][tx8]);
        const float4 bB = *reinterpret_cast<const float4*>(&Bs[k][tx8 + 4]);
        acc[0][0] += a0*bA.x; acc[0][1] += a0*bA.y; acc[0][2] += a0*bA.z; acc[0][3] += a0*bA.w;
        acc[0][4] += a0*bB.x; acc[0][5] += a0*bB.y; acc[0][6] += a0*bB.z; acc[0][7] += a0*bB.w;
        acc[1][0] += a1*bA.x; acc[1][1] += a1*bA.y; acc[1][2] += a1*bA.z; acc[1][3] += a1*bA.w;
        acc[1][4] += a1*bB.x; acc[1][5] += a1*bB.y; acc[1][6] += a1*bB.z; acc[1][7] += a1*bB.w;
        acc[2][0] += a2*bA.x; acc[2][1] += a2*bA.y; acc[2][2] += a2*bA.z; acc[2][3] += a2*bA.w;
        acc[2][4] += a2*bB.x; acc[2][5] += a2*bB.y; acc[2][6] += a2*bB.z; acc[2][7] += a2*bB.w;
        acc[3][0] += a3*bA.x; acc[3][1] += a3*bA.y; acc[3][2] += a3*bA.z; acc[3][3] += a3*bA.w;
        acc[3][4] += a3*bB.x; acc[3][5] += a3*bB.y; acc[3][6] += a3*bB.z; acc[3][7] += a3*bB.w;
      }
      __syncthreads();
    }
  }

  if (which < 2) {
    float* __restrict__ out = (which == 0) ? Qf : Kf;
#pragma unroll
    for (int i = 0; i < 4; ++i) {
      size_t base = (size_t)(tok0 + ty4 + i) * kD + dT + tx8;
      float4 v0 = {acc[i][0], acc[i][1], acc[i][2], acc[i][3]};
      float4 v1 = {acc[i][4], acc[i][5], acc[i][6], acc[i][7]};
      *reinterpret_cast<float4*>(&out[base]) = v0;
      *reinterpret_cast<float4*>(&out[base + 4]) = v1;
    }
  } else {
#pragma unroll
    for (int i = 0; i < 4; ++i) {
      size_t base = (size_t)(tok0 + ty4 + i) * kD + dT + tx8;
      ushort4 u0, u1;
      u0.x = f2bf_bits(acc[i][0]); u0.y = f2bf_bits(acc[i][1]);
      u0.z = f2bf_bits(acc[i][2]); u0.w = f2bf_bits(acc[i][3]);
      u1.x = f2bf_bits(acc[i][4]); u1.y = f2bf_bits(acc[i][5]);
      u1.z = f2bf_bits(acc[i][6]); u1.w = f2bf_bits(acc[i][7]);
      *reinterpret_cast<ushort4*>(&Vb[base]) = u0;
      *reinterpret_cast<ushort4*>(&Vb[base + 4]) = u1;
    }
  }
}

// ---------------------------------------------------------------------------
// K3: causal flash attention. grid (q-tile 32, head 16, batch 4), 64x64 tiles.
// Online softmax state (m,l) kept redundantly in registers per 16-thread row
// group (same wave -> identical values, no LDS races).
// ---------------------------------------------------------------------------
__global__ __launch_bounds__(256) void attn_kernel(
    const float* __restrict__ Qf,
    const float* __restrict__ Kf,
    const u16* __restrict__ Vb,
    u16* __restrict__ AOb)
{
  __shared__ float Qs[64][68], Ks[64][68], Vs[64][68], Ps[64][68];
  const int tid = threadIdx.x;
  const int tx = tid & 15, ty = tid >> 4;
  const int ty4 = ty * 4, tx4 = tx * 4;
  const int qt = blockIdx.x, hh = blockIdx.y, b = blockIdx.z;
  const size_t tokQ = (size_t)b * kS + (size_t)qt * 64;
  const int dh = hh * 64;

  {
    int idx = tid;
#pragma unroll
    for (int e = 0; e < 16; ++e, idx += 256) {
      int i = idx >> 6, d = idx & 63;
      Qs[i][d] = Qf[(tokQ + i) * kD + dh + d];
    }
  }

  float m[4], l[4], O[4][4];
#pragma unroll
  for (int i = 0; i < 4; ++i) {
    m[i] = -INFINITY; l[i] = 0.f;
#pragma unroll
    for (int j = 0; j < 4; ++j) O[i][j] = 0.f;
  }

#pragma unroll 1
  for (int kt = 0; kt <= qt; ++kt) {
    const size_t tokK = (size_t)b * kS + (size_t)kt * 64;
    __syncthreads();   // prior Ks/Vs/Ps consumers done
    {
      int idx = tid;
#pragma unroll
      for (int e = 0; e < 16; ++e, idx += 256) {
        int i = idx >> 6, d = idx & 63;
        Ks[i][d] = Kf[(tokK + i) * kD + dh + d];
        Vs[i][d] = bf2f(Vb[(tokK + i) * kD + dh + d]);
      }
    }
    __syncthreads();

    // S = Q K^T * 1/8
    float s[4][4] = {};
#pragma unroll 2
    for (int d0 = 0; d0 < 64; d0 += 4) {
      float4 a[4], bb[4];
#pragma unroll
      for (int i = 0; i < 4; ++i)
        a[i] = *reinterpret_cast<const float4*>(&Qs[ty4 + i][d0]);
#pragma unroll
      for (int j = 0; j < 4; ++j)
        bb[j] = *reinterpret_cast<const float4*>(&Ks[tx4 + j][d0]);
#pragma unroll
      for (int i = 0; i < 4; ++i)
#pragma unroll
        for (int j = 0; j < 4; ++j)
          s[i][j] += dot4(a[i], bb[j]);
    }
#pragma unroll
    for (int i = 0; i < 4; ++i)
#pragma unroll
      for (int j = 0; j < 4; ++j) s[i][j] *= 0.125f;

    if (kt == qt) {
#pragma unroll
      for (int i = 0; i < 4; ++i)
#pragma unroll
        for (int j = 0; j < 4; ++j)
          if (tx4 + j > ty4 + i) s[i][j] = -1e30f;
    }

    float alpha[4];
#pragma unroll
    for (int i = 0; i < 4; ++i) {
      float pm = fmaxf(fmaxf(s[i][0], s[i][1]), fmaxf(s[i][2], s[i][3]));
#pragma unroll
      for (int off = 1; off < 16; off <<= 1)
        pm = fmaxf(pm, __shfl_xor(pm, off, 64));
      float mn = fmaxf(m[i], pm);
      alpha[i] = __expf(m[i] - mn);
      m[i] = mn;
    }
#pragma unroll
    for (int i = 0; i < 4; ++i) {
      float p0 = __expf(s[i][0] - m[i]);
      float p1 = __expf(s[i][1] - m[i]);
      float p2 = __expf(s[i][2] - m[i]);
      float p3 = __expf(s[i][3] - m[i]);
      float r = p0 + p1 + p2 + p3;
#pragma unroll
      for (int off = 1; off < 16; off <<= 1)
        r += __shfl_xor(r, off, 64);
      l[i] = l[i] * alpha[i] + r;
#pragma unroll
      for (int j = 0; j < 4; ++j) O[i][j] *= alpha[i];
      float4 pv = {p0, p1, p2, p3};
      *reinterpret_cast<float4*>(&Ps[ty4 + i][tx4]) = pv;
    }
    __syncthreads();

    // O += P V   (O columns = d = tx4+j)
#pragma unroll 2
    for (int k0 = 0; k0 < 64; k0 += 4) {
      float4 a[4], v[4];
#pragma unroll
      for (int i = 0; i < 4; ++i)
        a[i] = *reinterpret_cast<const float4*>(&Ps[ty4 + i][k0]);
#pragma unroll
      for (int kk = 0; kk < 4; ++kk)
        v[kk] = *reinterpret_cast<const float4*>(&Vs[k0 + kk][tx4]);
#pragma unroll
      for (int i = 0; i < 4; ++i) {
        O[i][0] += a[i].x*v[0].x + a[i].y*v[1].x + a[i].z*v[2].x + a[i].w*v[3].x;
        O[i][1] += a[i].x*v[0].y + a[i].y*v[1].y + a[i].z*v[2].y + a[i].w*v[3].y;
        O[i][2] += a[i].x*v[0].z + a[i].y*v[1].z + a[i].z*v[2].z + a[i].w*v[3].z;
        O[i][3] += a[i].x*v[0].w + a[i].y*v[1].w + a[i].z*v[2].w + a[i].w*v[3].w;
      }
    }
  }

#pragma unroll
  for (int i = 0; i < 4; ++i) {
    float inv = 1.f / l[i];
    ushort4 u;
    u.x = f2bf_bits(O[i][0] * inv);
    u.y = f2bf_bits(O[i][1] * inv);
    u.z = f2bf_bits(O[i][2] * inv);
    u.w = f2bf_bits(O[i][3] * inv);
    *reinterpret_cast<ushort4*>(&AOb[(tokQ + ty4 + i) * kD + dh + tx4]) = u;
  }
}

// ---------------------------------------------------------------------------
// K4: out[t,d] = sum_e AO[t,e] * W_O[d,e]   (B^T-layout GEMM, fp32 out)
// ---------------------------------------------------------------------------
__global__ __launch_bounds__(256) void wo_kernel(
    const u16* __restrict__ AOb,
    const float* __restrict__ WO,
    float* __restrict__ out)
{
  __shared__ float As[64][17];
  __shared__ float Ws[16][129];   // [e][d], pad 129 -> benign conflicts
  const int tid = threadIdx.x;
  const int tx = tid & 15, ty = tid >> 4;
  const int ty4 = ty * 4, tx8 = tx * 8;
  const int dT = blockIdx.x * 128;
  const int tok0 = blockIdx.y * 64;

  float acc[4][8] = {};
  for (int e0 = 0; e0 < kD; e0 += 16) {
    {
      int idx = tid;
#pragma unroll
      for (int e = 0; e < 4; ++e, idx += 256) {
        int i = idx >> 4, k = idx & 15;
        As[i][k] = bf2f(AOb[(size_t)(tok0 + i) * kD + e0 + k]);
      }
      idx = tid;
#pragma unroll
      for (int e = 0; e < 8; ++e, idx += 256) {
        int dd = idx >> 4, ee = idx & 15;
        Ws[ee][dd] = WO[(size_t)(dT + dd) * kD + e0 + ee];
      }
    }
    __syncthreads();
#pragma unroll
    for (int k = 0; k < 16; ++k) {
      const float a0 = As[ty4 + 0][k];
      const float a1 = As[ty4 + 1][k];
      const float a2 = As[ty4 + 2][k];
      const float a3 = As[ty4 + 3][k];
#pragma unroll
      for (int j = 0; j < 8; ++j) {
        const float bj = Ws[k][tx8 + j];
        acc[0][j] += a0 * bj;
        acc[1][j] += a1 * bj;
        acc[2][j] += a2 * bj;
        acc[3][j] += a3 * bj;
      }
    }
    __syncthreads();
  }
#pragma unroll
  for (int i = 0; i < 4; ++i) {
    size_t base = (size_t)(tok0 + ty4 + i) * kD + dT + tx8;
    float4 v0 = {acc[i][0], acc[i][1], acc[i][2], acc[i][3]};
    float4 v1 = {acc[i][4], acc[i][5], acc[i][6], acc[i][7]};
    *reinterpret_cast<float4*>(&out[base]) = v0;
    *reinterpret_cast<float4*>(&out[base + 4]) = v1;
  }
}

// ---------------------------------------------------------------------------
extern "C" void kernel_launch(void* const* d_in, const int* in_sizes, int n_in,
                              void* d_out, int out_size, void* d_ws, size_t ws_size,
                              hipStream_t stream) {
  const float* x     = (const float*)d_in[0];
  const float* fqk_w = (const float*)d_in[1];
  const float* fv_w  = (const float*)d_in[2];
  const float* wq    = (const float*)d_in[3];
  const float* wk    = (const float*)d_in[4];
  const float* wv    = (const float*)d_in[5];
  const float* f_neu = (const float*)d_in[6];
  const float* r_neu = (const float*)d_in[7];
  const float* WO    = (const float*)d_in[8];
  float* out = (float*)d_out;

  // ws layout (100 MB): h_qk 2MB | h_v 2MB | Q f32 32MB | K f32 32MB | V bf16 16MB | AO bf16 16MB
  char* ws = (char*)d_ws;
  float* h_qk = (float*)(ws);
  float* h_v  = (float*)(ws + (size_t)(2u  << 20));
  float* Qf   = (float*)(ws + (size_t)(4u  << 20));
  float* Kf   = (float*)(ws + (size_t)(36u << 20));
  u16*   Vb   = (u16*)  (ws + (size_t)(68u << 20));
  u16*   AOb  = (u16*)  (ws + (size_t)(84u << 20));

  // h buffers are atomicAdd targets -> zero them (ws is poisoned every call)
  hipLaunchKernelGGL(zero_f32, dim3(1024), dim3(256), 0, stream, h_qk);
  hipLaunchKernelGGL(h_kernel, dim3(128, 8), dim3(256), 0, stream,
                     x, fqk_w, fv_w, f_neu, h_qk, h_v);
  hipLaunchKernelGGL(qkv_kernel, dim3(8, 128, 3), dim3(256), 0, stream,
                     h_qk, h_v, wq, wk, wv, r_neu, Qf, Kf, Vb);
  hipLaunchKernelGGL(attn_kernel, dim3(32, 16, 4), dim3(256), 0, stream,
                     Qf, Kf, Vb, AOb);
  hipLaunchKernelGGL(wo_kernel, dim3(8, 128), dim3(256), 0, stream,
                     AOb, WO, out);
}

// Round 3
// 1749.394 us; speedup vs baseline: 2.5057x; 2.5057x over previous
//
#include <hip/hip_runtime.h>
#include <hip/hip_bf16.h>

// AttentionCircuit round 3: bf16 MFMA for G/QKV/WO GEMMs, fp32 flash attention.
// Round-2 NaN root cause: B/A-staging used col=flat>>1,kq=(flat&1)*16 for a
// 128x32-short tile (4 x 16B segments per row) -> LDS OOB + uninitialized LDS
// read by MFMA. Fixed to col=flat>>2, kq=(flat&3)*8 in g_gemm, qkv_gemm, wo_gemm.

namespace {
constexpr int kS = 2048;
constexpr int kD = 1024;
}

typedef unsigned short u16;
typedef __attribute__((ext_vector_type(4))) float f32x4;
typedef __attribute__((ext_vector_type(8))) short s8v;   // 8 bf16 = 4 VGPRs

union FragU { s8v s; unsigned u[4]; };

__device__ __forceinline__ u16 f2bf_bits(float f) {
  union { float f; unsigned u; } cv; cv.f = f;
  unsigned u = cv.u;
  unsigned r = u + 0x7fffu + ((u >> 16) & 1u);   // RNE
  return (u16)(r >> 16);
}
__device__ __forceinline__ float bf2f(u16 b) {
  union { unsigned u; float f; } cv; cv.u = ((unsigned)b) << 16; return cv.f;
}
__device__ __forceinline__ unsigned pk_bf16(float a, float b) {
  __hip_bfloat162 h = __float22bfloat162_rn(make_float2(a, b));
  union { __hip_bfloat162 h; unsigned u; } cv; cv.h = h; return cv.u;
}
__device__ __forceinline__ float dot4(float4 a, float4 b) {
  return a.x*b.x + a.y*b.y + a.z*b.z + a.w*b.w;
}

// ---------------------------------------------------------------------------
// T1: FT[n*64+r][d] = f[n][d][r]  (bf16)  — B^T layout for G-GEMM.
// ---------------------------------------------------------------------------
__global__ __launch_bounds__(256) void t1_kernel(const float* __restrict__ f,
                                                 u16* __restrict__ FT) {
  __shared__ float Tt[64 * 132];
  const int tid = threadIdx.x;
  const int d0 = blockIdx.x * 128;
  const int n  = blockIdx.y;
#pragma unroll
  for (int e = 0; e < 8; ++e) {
    int flat = tid + e * 256;            // 0..2047
    int dd = flat >> 4, r4 = (flat & 15) * 4;
    float4 v = *(const float4*)&f[((size_t)n * kD + d0 + dd) * 64 + r4];
    Tt[(r4 + 0) * 132 + dd] = v.x;
    Tt[(r4 + 1) * 132 + dd] = v.y;
    Tt[(r4 + 2) * 132 + dd] = v.z;
    Tt[(r4 + 3) * 132 + dd] = v.w;
  }
  __syncthreads();
#pragma unroll
  for (int e = 0; e < 4; ++e) {
    int flat = tid + e * 256;            // 0..1023
    int r = flat >> 4, dq = (flat & 15) * 8;
    const float* p = &Tt[r * 132 + dq];
    uint4 o = { pk_bf16(p[0], p[1]), pk_bf16(p[2], p[3]),
                pk_bf16(p[4], p[5]), pk_bf16(p[6], p[7]) };
    *(uint4*)&FT[((size_t)n * 64 + r) * kD + d0 + dq] = o;
  }
}

// ---------------------------------------------------------------------------
// T2: RT[d][n*64+r] = r_neurons[n][r][d] (bf16) — B^T layout for QKV GEMM.
// ---------------------------------------------------------------------------
__global__ __launch_bounds__(256) void t2_kernel(const float* __restrict__ rn,
                                                 u16* __restrict__ RT) {
  __shared__ float Tt[128 * 68];
  const int tid = threadIdx.x;
  const int d0 = blockIdx.x * 128;
  const int n  = blockIdx.y;             // 0..63
#pragma unroll
  for (int e = 0; e < 8; ++e) {
    int flat = tid + e * 256;            // 0..2047
    int r = flat >> 5, d4 = (flat & 31) * 4;
    float4 v = *(const float4*)&rn[((size_t)n * 64 + r) * kD + d0 + d4];
    Tt[(d4 + 0) * 68 + r] = v.x;
    Tt[(d4 + 1) * 68 + r] = v.y;
    Tt[(d4 + 2) * 68 + r] = v.z;
    Tt[(d4 + 3) * 68 + r] = v.w;
  }
  __syncthreads();
#pragma unroll
  for (int e = 0; e < 4; ++e) {
    int flat = tid + e * 256;            // 0..1023
    int dd = flat >> 3, rq = (flat & 7) * 8;
    const float* p = &Tt[dd * 68 + rq];
    uint4 o = { pk_bf16(p[0], p[1]), pk_bf16(p[2], p[3]),
                pk_bf16(p[4], p[5]), pk_bf16(p[6], p[7]) };
    *(uint4*)&RT[((size_t)(d0 + dd)) * 4096 + n * 64 + rq] = o;
  }
}

// ---------------------------------------------------------------------------
// G-GEMM: G[t][g] = sum_d bf16(x[t,d]) * FT[g][d].  M=8192 K=1024 N=4096.
// 128x128 tile, BK=32, 4 waves (2x2), 16x16x32 bf16 MFMA.
// ---------------------------------------------------------------------------
__global__ __launch_bounds__(256) void g_gemm(const float* __restrict__ x,
                                              const u16* __restrict__ FT,
                                              u16* __restrict__ G) {
  __shared__ short As[128 * 40];
  __shared__ short Bs[128 * 40];
  const int tid = threadIdx.x;
  const int lane = tid & 63, wid = tid >> 6;
  const int wm = wid & 1, wn = wid >> 1;
  const int quad = lane >> 4, l15 = lane & 15;
  const int cT = blockIdx.x * 128;
  const int tok0 = blockIdx.y * 128;

  f32x4 acc[4][4];
#pragma unroll
  for (int mt = 0; mt < 4; ++mt)
#pragma unroll
    for (int nt = 0; nt < 4; ++nt) acc[mt][nt] = {0.f, 0.f, 0.f, 0.f};

#pragma unroll 1
  for (int d0 = 0; d0 < kD; d0 += 32) {
    __syncthreads();
#pragma unroll
    for (int e = 0; e < 4; ++e) {                 // A: x fp32 -> bf16
      int flat = tid + e * 256;                   // 0..1023 (float4 units)
      int row = flat >> 3, kq = (flat & 7) * 4;
      float4 v = *(const float4*)&x[(size_t)(tok0 + row) * kD + d0 + kq];
      uint2 o = { pk_bf16(v.x, v.y), pk_bf16(v.z, v.w) };
      *(uint2*)&As[row * 40 + kq] = o;
    }
#pragma unroll
    for (int e = 0; e < 2; ++e) {                 // B: FT bf16 direct
      int flat = tid + e * 256;                   // 0..511 (16B units, 4/row)
      int col = flat >> 2, kq = (flat & 3) * 8;
      *(s8v*)&Bs[col * 40 + kq] =
          *(const s8v*)&FT[(size_t)(cT + col) * kD + d0 + kq];
    }
    __syncthreads();
    s8v a[4], b[4];
#pragma unroll
    for (int mt = 0; mt < 4; ++mt)
      a[mt] = *(const s8v*)&As[(wm * 64 + mt * 16 + l15) * 40 + quad * 8];
#pragma unroll
    for (int nt = 0; nt < 4; ++nt)
      b[nt] = *(const s8v*)&Bs[(wn * 64 + nt * 16 + l15) * 40 + quad * 8];
#pragma unroll
    for (int mt = 0; mt < 4; ++mt)
#pragma unroll
      for (int nt = 0; nt < 4; ++nt)
        acc[mt][nt] = __builtin_amdgcn_mfma_f32_16x16x32_bf16(
            a[mt], b[nt], acc[mt][nt], 0, 0, 0);
  }
#pragma unroll
  for (int mt = 0; mt < 4; ++mt)
#pragma unroll
    for (int nt = 0; nt < 4; ++nt) {
      int col = cT + wn * 64 + nt * 16 + l15;
      int rbase = tok0 + wm * 64 + mt * 16 + quad * 4;
#pragma unroll
      for (int i = 0; i < 4; ++i)
        G[(size_t)(rbase + i) * 4096 + col] = f2bf_bits(acc[mt][nt][i]);
    }
}

// ---------------------------------------------------------------------------
// reduce_h: h_qk[t][r] = sum_n fqk_w[t][n]*G[t][n*64+r]; h_v from cols 2048+.
// ---------------------------------------------------------------------------
__global__ __launch_bounds__(256) void reduce_h(const u16* __restrict__ G,
                                                const float* __restrict__ fqk_w,
                                                const float* __restrict__ fv_w,
                                                float* __restrict__ h_qk,
                                                float* __restrict__ h_v) {
  int idx = blockIdx.x * 256 + threadIdx.x;    // 0..131071
  int t = idx >> 4, r4 = (idx & 15) * 4;
  float4 aq = {0.f, 0.f, 0.f, 0.f}, av = {0.f, 0.f, 0.f, 0.f};
  const u16* gq = &G[(size_t)t * 4096 + r4];
  const u16* gv = gq + 2048;
#pragma unroll 4
  for (int n = 0; n < 32; ++n) {
    float wa = fqk_w[t * 32 + n];
    float wb = fv_w[t * 32 + n];
    ushort4 g1 = *(const ushort4*)&gq[n * 64];
    ushort4 g2 = *(const ushort4*)&gv[n * 64];
    aq.x += wa * bf2f(g1.x); aq.y += wa * bf2f(g1.y);
    aq.z += wa * bf2f(g1.z); aq.w += wa * bf2f(g1.w);
    av.x += wb * bf2f(g2.x); av.y += wb * bf2f(g2.y);
    av.z += wb * bf2f(g2.z); av.w += wb * bf2f(g2.w);
  }
  *(float4*)&h_qk[t * 64 + r4] = aq;
  *(float4*)&h_v[t * 64 + r4] = av;
}

// ---------------------------------------------------------------------------
// QKV-GEMM: C[t][d] = sum_g (w[t,n]*h[t,r]) * RT[d][g0+g],  g=n*64+r, K=2048.
// A-fragments synthesized in registers from LDS h (fp32) and w tiles.
// z: 0->Q fp32, 1->K fp32, 2->V bf16.
// ---------------------------------------------------------------------------
__global__ __launch_bounds__(256) void qkv_gemm(
    const float* __restrict__ h_qk, const float* __restrict__ h_v,
    const float* __restrict__ wq, const float* __restrict__ wk,
    const float* __restrict__ wv, const u16* __restrict__ RT,
    float* __restrict__ Qf, float* __restrict__ Kf, u16* __restrict__ Vb) {
  __shared__ float hs[128 * 68];
  __shared__ float wsl[128 * 33];
  __shared__ short Bs[128 * 40];
  const int tid = threadIdx.x;
  const int lane = tid & 63, wid = tid >> 6;
  const int wm = wid & 1, wn = wid >> 1;
  const int quad = lane >> 4, l15 = lane & 15;
  const int dT = blockIdx.x * 128;
  const int tok0 = blockIdx.y * 128;
  const int which = blockIdx.z;
  const float* __restrict__ h = (which == 2) ? h_v : h_qk;
  const float* __restrict__ w = (which == 0) ? wq : (which == 1) ? wk : wv;
  const int g0 = (which == 2) ? 2048 : 0;

#pragma unroll
  for (int e = 0; e < 8; ++e) {                  // h tile: 128x64 fp32
    int flat = tid + e * 256;                    // 0..2047 (float4 units)
    int row = flat >> 4, rq = (flat & 15) * 4;
    *(float4*)&hs[row * 68 + rq] =
        *(const float4*)&h[(size_t)(tok0 + row) * 64 + rq];
  }
#pragma unroll
  for (int e = 0; e < 16; ++e) {                 // w tile: 128x32 fp32
    int flat = tid + e * 256;                    // 0..4095
    int row = flat >> 5, nn = flat & 31;
    wsl[row * 33 + nn] = w[(size_t)(tok0 + row) * 32 + nn];
  }

  f32x4 acc[4][4];
#pragma unroll
  for (int mt = 0; mt < 4; ++mt)
#pragma unroll
    for (int nt = 0; nt < 4; ++nt) acc[mt][nt] = {0.f, 0.f, 0.f, 0.f};

#pragma unroll 1
  for (int ks = 0; ks < 64; ++ks) {
    const int nA = ks >> 1, r0 = (ks & 1) * 32;
    __syncthreads();
#pragma unroll
    for (int e = 0; e < 2; ++e) {
      int flat = tid + e * 256;                  // 0..511 (16B units, 4/row)
      int col = flat >> 2, kq = (flat & 3) * 8;
      *(s8v*)&Bs[col * 40 + kq] =
          *(const s8v*)&RT[(size_t)(dT + col) * 4096 + g0 + ks * 32 + kq];
    }
    __syncthreads();
    s8v a[4], b[4];
#pragma unroll
    for (int mt = 0; mt < 4; ++mt) {
      int row = wm * 64 + mt * 16 + l15;
      float wv_ = wsl[row * 33 + nA];
      const float* hp = &hs[row * 68 + r0 + quad * 8];
      FragU fa;
      fa.u[0] = pk_bf16(wv_ * hp[0], wv_ * hp[1]);
      fa.u[1] = pk_bf16(wv_ * hp[2], wv_ * hp[3]);
      fa.u[2] = pk_bf16(wv_ * hp[4], wv_ * hp[5]);
      fa.u[3] = pk_bf16(wv_ * hp[6], wv_ * hp[7]);
      a[mt] = fa.s;
    }
#pragma unroll
    for (int nt = 0; nt < 4; ++nt)
      b[nt] = *(const s8v*)&Bs[(wn * 64 + nt * 16 + l15) * 40 + quad * 8];
#pragma unroll
    for (int mt = 0; mt < 4; ++mt)
#pragma unroll
      for (int nt = 0; nt < 4; ++nt)
        acc[mt][nt] = __builtin_amdgcn_mfma_f32_16x16x32_bf16(
            a[mt], b[nt], acc[mt][nt], 0, 0, 0);
  }

  if (which < 2) {
    float* __restrict__ O = (which == 0) ? Qf : Kf;
#pragma unroll
    for (int mt = 0; mt < 4; ++mt)
#pragma unroll
      for (int nt = 0; nt < 4; ++nt) {
        int col = dT + wn * 64 + nt * 16 + l15;
        int rbase = tok0 + wm * 64 + mt * 16 + quad * 4;
#pragma unroll
        for (int i = 0; i < 4; ++i)
          O[(size_t)(rbase + i) * kD + col] = acc[mt][nt][i];
      }
  } else {
#pragma unroll
    for (int mt = 0; mt < 4; ++mt)
#pragma unroll
      for (int nt = 0; nt < 4; ++nt) {
        int col = dT + wn * 64 + nt * 16 + l15;
        int rbase = tok0 + wm * 64 + mt * 16 + quad * 4;
#pragma unroll
        for (int i = 0; i < 4; ++i)
          Vb[(size_t)(rbase + i) * kD + col] = f2bf_bits(acc[mt][nt][i]);
      }
  }
}

// ---------------------------------------------------------------------------
// K3: causal flash attention (fp32, verified round 1, unchanged).
// ---------------------------------------------------------------------------
__global__ __launch_bounds__(256) void attn_kernel(
    const float* __restrict__ Qf,
    const float* __restrict__ Kf,
    const u16* __restrict__ Vb,
    u16* __restrict__ AOb)
{
  __shared__ float Qs[64][68], Ks[64][68], Vs[64][68], Ps[64][68];
  const int tid = threadIdx.x;
  const int tx = tid & 15, ty = tid >> 4;
  const int ty4 = ty * 4, tx4 = tx * 4;
  const int qt = blockIdx.x, hh = blockIdx.y, b = blockIdx.z;
  const size_t tokQ = (size_t)b * kS + (size_t)qt * 64;
  const int dh = hh * 64;

  {
    int idx = tid;
#pragma unroll
    for (int e = 0; e < 16; ++e, idx += 256) {
      int i = idx >> 6, d = idx & 63;
      Qs[i][d] = Qf[(tokQ + i) * kD + dh + d];
    }
  }

  float m[4], l[4], O[4][4];
#pragma unroll
  for (int i = 0; i < 4; ++i) {
    m[i] = -INFINITY; l[i] = 0.f;
#pragma unroll
    for (int j = 0; j < 4; ++j) O[i][j] = 0.f;
  }

#pragma unroll 1
  for (int kt = 0; kt <= qt; ++kt) {
    const size_t tokK = (size_t)b * kS + (size_t)kt * 64;
    __syncthreads();
    {
      int idx = tid;
#pragma unroll
      for (int e = 0; e < 16; ++e, idx += 256) {
        int i = idx >> 6, d = idx & 63;
        Ks[i][d] = Kf[(tokK + i) * kD + dh + d];
        Vs[i][d] = bf2f(Vb[(tokK + i) * kD + dh + d]);
      }
    }
    __syncthreads();

    float s[4][4] = {};
#pragma unroll 2
    for (int d0 = 0; d0 < 64; d0 += 4) {
      float4 a[4], bb[4];
#pragma unroll
      for (int i = 0; i < 4; ++i)
        a[i] = *reinterpret_cast<const float4*>(&Qs[ty4 + i][d0]);
#pragma unroll
      for (int j = 0; j < 4; ++j)
        bb[j] = *reinterpret_cast<const float4*>(&Ks[tx4 + j][d0]);
#pragma unroll
      for (int i = 0; i < 4; ++i)
#pragma unroll
        for (int j = 0; j < 4; ++j)
          s[i][j] += dot4(a[i], bb[j]);
    }
#pragma unroll
    for (int i = 0; i < 4; ++i)
#pragma unroll
      for (int j = 0; j < 4; ++j) s[i][j] *= 0.125f;

    if (kt == qt) {
#pragma unroll
      for (int i = 0; i < 4; ++i)
#pragma unroll
        for (int j = 0; j < 4; ++j)
          if (tx4 + j > ty4 + i) s[i][j] = -1e30f;
    }

    float alpha[4];
#pragma unroll
    for (int i = 0; i < 4; ++i) {
      float pm = fmaxf(fmaxf(s[i][0], s[i][1]), fmaxf(s[i][2], s[i][3]));
#pragma unroll
      for (int off = 1; off < 16; off <<= 1)
        pm = fmaxf(pm, __shfl_xor(pm, off, 64));
      float mn = fmaxf(m[i], pm);
      alpha[i] = __expf(m[i] - mn);
      m[i] = mn;
    }
#pragma unroll
    for (int i = 0; i < 4; ++i) {
      float p0 = __expf(s[i][0] - m[i]);
      float p1 = __expf(s[i][1] - m[i]);
      float p2 = __expf(s[i][2] - m[i]);
      float p3 = __expf(s[i][3] - m[i]);
      float r = p0 + p1 + p2 + p3;
#pragma unroll
      for (int off = 1; off < 16; off <<= 1)
        r += __shfl_xor(r, off, 64);
      l[i] = l[i] * alpha[i] + r;
#pragma unroll
      for (int j = 0; j < 4; ++j) O[i][j] *= alpha[i];
      float4 pv = {p0, p1, p2, p3};
      *reinterpret_cast<float4*>(&Ps[ty4 + i][tx4]) = pv;
    }
    __syncthreads();

#pragma unroll 2
    for (int k0 = 0; k0 < 64; k0 += 4) {
      float4 a[4], v[4];
#pragma unroll
      for (int i = 0; i < 4; ++i)
        a[i] = *reinterpret_cast<const float4*>(&Ps[ty4 + i][k0]);
#pragma unroll
      for (int kk = 0; kk < 4; ++kk)
        v[kk] = *reinterpret_cast<const float4*>(&Vs[k0 + kk][tx4]);
#pragma unroll
      for (int i = 0; i < 4; ++i) {
        O[i][0] += a[i].x*v[0].x + a[i].y*v[1].x + a[i].z*v[2].x + a[i].w*v[3].x;
        O[i][1] += a[i].x*v[0].y + a[i].y*v[1].y + a[i].z*v[2].y + a[i].w*v[3].y;
        O[i][2] += a[i].x*v[0].z + a[i].y*v[1].z + a[i].z*v[2].z + a[i].w*v[3].z;
        O[i][3] += a[i].x*v[0].w + a[i].y*v[1].w + a[i].z*v[2].w + a[i].w*v[3].w;
      }
    }
  }

#pragma unroll
  for (int i = 0; i < 4; ++i) {
    float inv = 1.f / l[i];
    ushort4 u;
    u.x = f2bf_bits(O[i][0] * inv);
    u.y = f2bf_bits(O[i][1] * inv);
    u.z = f2bf_bits(O[i][2] * inv);
    u.w = f2bf_bits(O[i][3] * inv);
    *reinterpret_cast<ushort4*>(&AOb[(tokQ + ty4 + i) * kD + dh + tx4]) = u;
  }
}

// ---------------------------------------------------------------------------
// WO-GEMM: out[t][d] = sum_e AO[t][e] * W_O[d][e].  W_O is already B^T layout.
// ---------------------------------------------------------------------------
__global__ __launch_bounds__(256) void wo_gemm(const u16* __restrict__ AOb,
                                               const float* __restrict__ WO,
                                               float* __restrict__ out) {
  __shared__ short As[128 * 40];
  __shared__ short Bs[128 * 40];
  const int tid = threadIdx.x;
  const int lane = tid & 63, wid = tid >> 6;
  const int wm = wid & 1, wn = wid >> 1;
  const int quad = lane >> 4, l15 = lane & 15;
  const int dT = blockIdx.x * 128;
  const int tok0 = blockIdx.y * 128;

  f32x4 acc[4][4];
#pragma unroll
  for (int mt = 0; mt < 4; ++mt)
#pragma unroll
    for (int nt = 0; nt < 4; ++nt) acc[mt][nt] = {0.f, 0.f, 0.f, 0.f};

#pragma unroll 1
  for (int e0 = 0; e0 < kD; e0 += 32) {
    __syncthreads();
#pragma unroll
    for (int e = 0; e < 2; ++e) {                 // A: AO bf16 direct
      int flat = tid + e * 256;                   // 0..511 (16B units, 4/row)
      int row = flat >> 2, kq = (flat & 3) * 8;
      *(s8v*)&As[row * 40 + kq] =
          *(const s8v*)&AOb[(size_t)(tok0 + row) * kD + e0 + kq];
    }
#pragma unroll
    for (int e = 0; e < 4; ++e) {                 // B: W_O fp32 -> bf16
      int flat = tid + e * 256;                   // 0..1023 (float4 units)
      int col = flat >> 3, kq = (flat & 7) * 4;
      float4 v = *(const float4*)&WO[(size_t)(dT + col) * kD + e0 + kq];
      uint2 o = { pk_bf16(v.x, v.y), pk_bf16(v.z, v.w) };
      *(uint2*)&Bs[col * 40 + kq] = o;
    }
    __syncthreads();
    s8v a[4], b[4];
#pragma unroll
    for (int mt = 0; mt < 4; ++mt)
      a[mt] = *(const s8v*)&As[(wm * 64 + mt * 16 + l15) * 40 + quad * 8];
#pragma unroll
    for (int nt = 0; nt < 4; ++nt)
      b[nt] = *(const s8v*)&Bs[(wn * 64 + nt * 16 + l15) * 40 + quad * 8];
#pragma unroll
    for (int mt = 0; mt < 4; ++mt)
#pragma unroll
      for (int nt = 0; nt < 4; ++nt)
        acc[mt][nt] = __builtin_amdgcn_mfma_f32_16x16x32_bf16(
            a[mt], b[nt], acc[mt][nt], 0, 0, 0);
  }
#pragma unroll
  for (int mt = 0; mt < 4; ++mt)
#pragma unroll
    for (int nt = 0; nt < 4; ++nt) {
      int col = dT + wn * 64 + nt * 16 + l15;
      int rbase = tok0 + wm * 64 + mt * 16 + quad * 4;
#pragma unroll
      for (int i = 0; i < 4; ++i)
        out[(size_t)(rbase + i) * kD + col] = acc[mt][nt][i];
    }
}

// ---------------------------------------------------------------------------
extern "C" void kernel_launch(void* const* d_in, const int* in_sizes, int n_in,
                              void* d_out, int out_size, void* d_ws, size_t ws_size,
                              hipStream_t stream) {
  const float* x     = (const float*)d_in[0];
  const float* fqk_w = (const float*)d_in[1];
  const float* fv_w  = (const float*)d_in[2];
  const float* wq    = (const float*)d_in[3];
  const float* wk    = (const float*)d_in[4];
  const float* wv    = (const float*)d_in[5];
  const float* f_neu = (const float*)d_in[6];
  const float* r_neu = (const float*)d_in[7];
  const float* WO    = (const float*)d_in[8];
  float* out = (float*)d_out;

  // ws layout (100 MB, lifetime-overlapped):
  //  [0,8)    FT  (dead after g_gemm)      -> AOb [0,16) for attn/wo
  //  [8,16)   RT  (dead after qkv_gemm)
  //  [16,80)  G   (dead after reduce_h)    -> Qf [16,48), Kf [48,80)
  //  [80,84)  h_qk, h_v
  //  [84,100) Vb
  char* ws = (char*)d_ws;
  u16*   FT   = (u16*)  (ws);
  u16*   RT   = (u16*)  (ws + ((size_t)8u  << 20));
  u16*   G    = (u16*)  (ws + ((size_t)16u << 20));
  float* h_qk = (float*)(ws + ((size_t)80u << 20));
  float* h_v  = (float*)(ws + ((size_t)82u << 20));
  float* Qf   = (float*)(ws + ((size_t)16u << 20));
  float* Kf   = (float*)(ws + ((size_t)48u << 20));
  u16*   Vb   = (u16*)  (ws + ((size_t)84u << 20));
  u16*   AOb  = (u16*)  (ws);

  hipLaunchKernelGGL(t1_kernel, dim3(8, 64), dim3(256), 0, stream, f_neu, FT);
  hipLaunchKernelGGL(t2_kernel, dim3(8, 64), dim3(256), 0, stream, r_neu, RT);
  hipLaunchKernelGGL(g_gemm, dim3(32, 64), dim3(256), 0, stream, x, FT, G);
  hipLaunchKernelGGL(reduce_h, dim3(512), dim3(256), 0, stream,
                     G, fqk_w, fv_w, h_qk, h_v);
  hipLaunchKernelGGL(qkv_gemm, dim3(8, 64, 3), dim3(256), 0, stream,
                     h_qk, h_v, wq, wk, wv, RT, Qf, Kf, Vb);
  hipLaunchKernelGGL(attn_kernel, dim3(32, 16, 4), dim3(256), 0, stream,
                     Qf, Kf, Vb, AOb);
  hipLaunchKernelGGL(wo_gemm, dim3(8, 64), dim3(256), 0, stream,
                     AOb, WO, out);
}

// Round 4
// 700.239 us; speedup vs baseline: 6.2601x; 2.4983x over previous
//
#include <hip/hip_runtime.h>
#include <hip/hip_bf16.h>

// AttentionCircuit round 4: MFMA flash attention (bf16 QK^T and PV, fp32
// online softmax), Q/K stored bf16, V stored transposed [b][h][d][s] by
// qkv_gemm so attention's V^T staging is coalesced. GEMMs as in round 3.

namespace {
constexpr int kS = 2048;
constexpr int kD = 1024;
}

typedef unsigned short u16;
typedef __attribute__((ext_vector_type(4))) float f32x4;
typedef __attribute__((ext_vector_type(8))) short s8v;   // 8 bf16 = 4 VGPRs

union FragU { s8v s; unsigned u[4]; };

__device__ __forceinline__ u16 f2bf_bits(float f) {
  union { float f; unsigned u; } cv; cv.f = f;
  unsigned u = cv.u;
  unsigned r = u + 0x7fffu + ((u >> 16) & 1u);   // RNE
  return (u16)(r >> 16);
}
__device__ __forceinline__ float bf2f(u16 b) {
  union { unsigned u; float f; } cv; cv.u = ((unsigned)b) << 16; return cv.f;
}
__device__ __forceinline__ unsigned pk_bf16(float a, float b) {
  __hip_bfloat162 h = __float22bfloat162_rn(make_float2(a, b));
  union { __hip_bfloat162 h; unsigned u; } cv; cv.h = h; return cv.u;
}

// ---------------------------------------------------------------------------
// T1: FT[n*64+r][d] = f[n][d][r]  (bf16)  — B^T layout for G-GEMM.
// ---------------------------------------------------------------------------
__global__ __launch_bounds__(256) void t1_kernel(const float* __restrict__ f,
                                                 u16* __restrict__ FT) {
  __shared__ float Tt[64 * 132];
  const int tid = threadIdx.x;
  const int d0 = blockIdx.x * 128;
  const int n  = blockIdx.y;
#pragma unroll
  for (int e = 0; e < 8; ++e) {
    int flat = tid + e * 256;            // 0..2047
    int dd = flat >> 4, r4 = (flat & 15) * 4;
    float4 v = *(const float4*)&f[((size_t)n * kD + d0 + dd) * 64 + r4];
    Tt[(r4 + 0) * 132 + dd] = v.x;
    Tt[(r4 + 1) * 132 + dd] = v.y;
    Tt[(r4 + 2) * 132 + dd] = v.z;
    Tt[(r4 + 3) * 132 + dd] = v.w;
  }
  __syncthreads();
#pragma unroll
  for (int e = 0; e < 4; ++e) {
    int flat = tid + e * 256;            // 0..1023
    int r = flat >> 4, dq = (flat & 15) * 8;
    const float* p = &Tt[r * 132 + dq];
    uint4 o = { pk_bf16(p[0], p[1]), pk_bf16(p[2], p[3]),
                pk_bf16(p[4], p[5]), pk_bf16(p[6], p[7]) };
    *(uint4*)&FT[((size_t)n * 64 + r) * kD + d0 + dq] = o;
  }
}

// ---------------------------------------------------------------------------
// T2: RT[d][n*64+r] = r_neurons[n][r][d] (bf16) — B^T layout for QKV GEMM.
// ---------------------------------------------------------------------------
__global__ __launch_bounds__(256) void t2_kernel(const float* __restrict__ rn,
                                                 u16* __restrict__ RT) {
  __shared__ float Tt[128 * 68];
  const int tid = threadIdx.x;
  const int d0 = blockIdx.x * 128;
  const int n  = blockIdx.y;             // 0..63
#pragma unroll
  for (int e = 0; e < 8; ++e) {
    int flat = tid + e * 256;            // 0..2047
    int r = flat >> 5, d4 = (flat & 31) * 4;
    float4 v = *(const float4*)&rn[((size_t)n * 64 + r) * kD + d0 + d4];
    Tt[(d4 + 0) * 68 + r] = v.x;
    Tt[(d4 + 1) * 68 + r] = v.y;
    Tt[(d4 + 2) * 68 + r] = v.z;
    Tt[(d4 + 3) * 68 + r] = v.w;
  }
  __syncthreads();
#pragma unroll
  for (int e = 0; e < 4; ++e) {
    int flat = tid + e * 256;            // 0..1023
    int dd = flat >> 3, rq = (flat & 7) * 8;
    const float* p = &Tt[dd * 68 + rq];
    uint4 o = { pk_bf16(p[0], p[1]), pk_bf16(p[2], p[3]),
                pk_bf16(p[4], p[5]), pk_bf16(p[6], p[7]) };
    *(uint4*)&RT[((size_t)(d0 + dd)) * 4096 + n * 64 + rq] = o;
  }
}

// ---------------------------------------------------------------------------
// G-GEMM: G[t][g] = sum_d bf16(x[t,d]) * FT[g][d].  M=8192 K=1024 N=4096.
// ---------------------------------------------------------------------------
__global__ __launch_bounds__(256) void g_gemm(const float* __restrict__ x,
                                              const u16* __restrict__ FT,
                                              u16* __restrict__ G) {
  __shared__ short As[128 * 40];
  __shared__ short Bs[128 * 40];
  const int tid = threadIdx.x;
  const int lane = tid & 63, wid = tid >> 6;
  const int wm = wid & 1, wn = wid >> 1;
  const int quad = lane >> 4, l15 = lane & 15;
  const int cT = blockIdx.x * 128;
  const int tok0 = blockIdx.y * 128;

  f32x4 acc[4][4];
#pragma unroll
  for (int mt = 0; mt < 4; ++mt)
#pragma unroll
    for (int nt = 0; nt < 4; ++nt) acc[mt][nt] = {0.f, 0.f, 0.f, 0.f};

#pragma unroll 1
  for (int d0 = 0; d0 < kD; d0 += 32) {
    __syncthreads();
#pragma unroll
    for (int e = 0; e < 4; ++e) {                 // A: x fp32 -> bf16
      int flat = tid + e * 256;                   // 0..1023 (float4 units)
      int row = flat >> 3, kq = (flat & 7) * 4;
      float4 v = *(const float4*)&x[(size_t)(tok0 + row) * kD + d0 + kq];
      uint2 o = { pk_bf16(v.x, v.y), pk_bf16(v.z, v.w) };
      *(uint2*)&As[row * 40 + kq] = o;
    }
#pragma unroll
    for (int e = 0; e < 2; ++e) {                 // B: FT bf16 direct
      int flat = tid + e * 256;                   // 0..511 (16B units, 4/row)
      int col = flat >> 2, kq = (flat & 3) * 8;
      *(s8v*)&Bs[col * 40 + kq] =
          *(const s8v*)&FT[(size_t)(cT + col) * kD + d0 + kq];
    }
    __syncthreads();
    s8v a[4], b[4];
#pragma unroll
    for (int mt = 0; mt < 4; ++mt)
      a[mt] = *(const s8v*)&As[(wm * 64 + mt * 16 + l15) * 40 + quad * 8];
#pragma unroll
    for (int nt = 0; nt < 4; ++nt)
      b[nt] = *(const s8v*)&Bs[(wn * 64 + nt * 16 + l15) * 40 + quad * 8];
#pragma unroll
    for (int mt = 0; mt < 4; ++mt)
#pragma unroll
      for (int nt = 0; nt < 4; ++nt)
        acc[mt][nt] = __builtin_amdgcn_mfma_f32_16x16x32_bf16(
            a[mt], b[nt], acc[mt][nt], 0, 0, 0);
  }
#pragma unroll
  for (int mt = 0; mt < 4; ++mt)
#pragma unroll
    for (int nt = 0; nt < 4; ++nt) {
      int col = cT + wn * 64 + nt * 16 + l15;
      int rbase = tok0 + wm * 64 + mt * 16 + quad * 4;
#pragma unroll
      for (int i = 0; i < 4; ++i)
        G[(size_t)(rbase + i) * 4096 + col] = f2bf_bits(acc[mt][nt][i]);
    }
}

// ---------------------------------------------------------------------------
// reduce_h: h_qk[t][r] = sum_n fqk_w[t][n]*G[t][n*64+r]; h_v from cols 2048+.
// ---------------------------------------------------------------------------
__global__ __launch_bounds__(256) void reduce_h(const u16* __restrict__ G,
                                                const float* __restrict__ fqk_w,
                                                const float* __restrict__ fv_w,
                                                float* __restrict__ h_qk,
                                                float* __restrict__ h_v) {
  int idx = blockIdx.x * 256 + threadIdx.x;    // 0..131071
  int t = idx >> 4, r4 = (idx & 15) * 4;
  float4 aq = {0.f, 0.f, 0.f, 0.f}, av = {0.f, 0.f, 0.f, 0.f};
  const u16* gq = &G[(size_t)t * 4096 + r4];
  const u16* gv = gq + 2048;
#pragma unroll 4
  for (int n = 0; n < 32; ++n) {
    float wa = fqk_w[t * 32 + n];
    float wb = fv_w[t * 32 + n];
    ushort4 g1 = *(const ushort4*)&gq[n * 64];
    ushort4 g2 = *(const ushort4*)&gv[n * 64];
    aq.x += wa * bf2f(g1.x); aq.y += wa * bf2f(g1.y);
    aq.z += wa * bf2f(g1.z); aq.w += wa * bf2f(g1.w);
    av.x += wb * bf2f(g2.x); av.y += wb * bf2f(g2.y);
    av.z += wb * bf2f(g2.z); av.w += wb * bf2f(g2.w);
  }
  *(float4*)&h_qk[t * 64 + r4] = aq;
  *(float4*)&h_v[t * 64 + r4] = av;
}

// ---------------------------------------------------------------------------
// QKV-GEMM: C[t][d] = sum_g (w[t,n]*h[t,r]) * RT[d][g0+g],  g=n*64+r, K=2048.
// which: 0->Qb (bf16, [t][d]), 1->Kb (bf16, [t][d]), 2->VTg (bf16, [b][h][d][s]).
// ---------------------------------------------------------------------------
__global__ __launch_bounds__(256) void qkv_gemm(
    const float* __restrict__ h_qk, const float* __restrict__ h_v,
    const float* __restrict__ wq, const float* __restrict__ wk,
    const float* __restrict__ wv, const u16* __restrict__ RT,
    u16* __restrict__ Qb, u16* __restrict__ Kb, u16* __restrict__ VTg) {
  __shared__ float hs[128 * 68];
  __shared__ float wsl[128 * 33];
  __shared__ short Bs[128 * 40];
  const int tid = threadIdx.x;
  const int lane = tid & 63, wid = tid >> 6;
  const int wm = wid & 1, wn = wid >> 1;
  const int quad = lane >> 4, l15 = lane & 15;
  const int dT = blockIdx.x * 128;
  const int tok0 = blockIdx.y * 128;
  const int which = blockIdx.z;
  const float* __restrict__ h = (which == 2) ? h_v : h_qk;
  const float* __restrict__ w = (which == 0) ? wq : (which == 1) ? wk : wv;
  const int g0 = (which == 2) ? 2048 : 0;

#pragma unroll
  for (int e = 0; e < 8; ++e) {                  // h tile: 128x64 fp32
    int flat = tid + e * 256;                    // 0..2047 (float4 units)
    int row = flat >> 4, rq = (flat & 15) * 4;
    *(float4*)&hs[row * 68 + rq] =
        *(const float4*)&h[(size_t)(tok0 + row) * 64 + rq];
  }
#pragma unroll
  for (int e = 0; e < 16; ++e) {                 // w tile: 128x32 fp32
    int flat = tid + e * 256;                    // 0..4095
    int row = flat >> 5, nn = flat & 31;
    wsl[row * 33 + nn] = w[(size_t)(tok0 + row) * 32 + nn];
  }

  f32x4 acc[4][4];
#pragma unroll
  for (int mt = 0; mt < 4; ++mt)
#pragma unroll
    for (int nt = 0; nt < 4; ++nt) acc[mt][nt] = {0.f, 0.f, 0.f, 0.f};

#pragma unroll 1
  for (int ks = 0; ks < 64; ++ks) {
    const int nA = ks >> 1, r0 = (ks & 1) * 32;
    __syncthreads();
#pragma unroll
    for (int e = 0; e < 2; ++e) {
      int flat = tid + e * 256;                  // 0..511 (16B units, 4/row)
      int col = flat >> 2, kq = (flat & 3) * 8;
      *(s8v*)&Bs[col * 40 + kq] =
          *(const s8v*)&RT[(size_t)(dT + col) * 4096 + g0 + ks * 32 + kq];
    }
    __syncthreads();
    s8v a[4], b[4];
#pragma unroll
    for (int mt = 0; mt < 4; ++mt) {
      int row = wm * 64 + mt * 16 + l15;
      float wv_ = wsl[row * 33 + nA];
      const float* hp = &hs[row * 68 + r0 + quad * 8];
      FragU fa;
      fa.u[0] = pk_bf16(wv_ * hp[0], wv_ * hp[1]);
      fa.u[1] = pk_bf16(wv_ * hp[2], wv_ * hp[3]);
      fa.u[2] = pk_bf16(wv_ * hp[4], wv_ * hp[5]);
      fa.u[3] = pk_bf16(wv_ * hp[6], wv_ * hp[7]);
      a[mt] = fa.s;
    }
#pragma unroll
    for (int nt = 0; nt < 4; ++nt)
      b[nt] = *(const s8v*)&Bs[(wn * 64 + nt * 16 + l15) * 40 + quad * 8];
#pragma unroll
    for (int mt = 0; mt < 4; ++mt)
#pragma unroll
      for (int nt = 0; nt < 4; ++nt)
        acc[mt][nt] = __builtin_amdgcn_mfma_f32_16x16x32_bf16(
            a[mt], b[nt], acc[mt][nt], 0, 0, 0);
  }

  if (which < 2) {
    u16* __restrict__ O = (which == 0) ? Qb : Kb;
#pragma unroll
    for (int mt = 0; mt < 4; ++mt)
#pragma unroll
      for (int nt = 0; nt < 4; ++nt) {
        int col = dT + wn * 64 + nt * 16 + l15;
        int rbase = tok0 + wm * 64 + mt * 16 + quad * 4;
#pragma unroll
        for (int i = 0; i < 4; ++i)
          O[(size_t)(rbase + i) * kD + col] = f2bf_bits(acc[mt][nt][i]);
      }
  } else {
#pragma unroll
    for (int mt = 0; mt < 4; ++mt)
#pragma unroll
      for (int nt = 0; nt < 4; ++nt) {
        int d = dT + wn * 64 + nt * 16 + l15;
        int hh = d >> 6, dl = d & 63;
        int t = tok0 + wm * 64 + mt * 16 + quad * 4;   // 4 consecutive tokens
        int bb = t >> 11, sl = t & 2047;
        ushort4 u = { f2bf_bits(acc[mt][nt][0]), f2bf_bits(acc[mt][nt][1]),
                      f2bf_bits(acc[mt][nt][2]), f2bf_bits(acc[mt][nt][3]) };
        *(ushort4*)&VTg[(((size_t)bb * 16 + hh) * 64 + dl) * kS + sl] = u;
      }
  }
}

// ---------------------------------------------------------------------------
// Flash attention, MFMA. Block = (qt, head, batch), 64 q-rows; wave w owns
// rows w*16..w*16+15. K token-major (=B^T layout), V staged from VTg [d][s].
// P round-trips C-layout -> A-layout through a per-wave LDS strip.
// ---------------------------------------------------------------------------
__global__ __launch_bounds__(256) void attn_mfma(
    const u16* __restrict__ Qb, const u16* __restrict__ Kb,
    const u16* __restrict__ VTg, u16* __restrict__ AOb)
{
  __shared__ short Qs[64 * 72];       // [q-row][d]   stride 72 shorts = 144 B
  __shared__ short Ks[64 * 72];       // [k-tok][d]
  __shared__ short VTs[64 * 72];      // [d][k-tok]
  __shared__ short Ps[4][16 * 72];    // per-wave P strip, [q-row-local][k-tok]
  const int tid = threadIdx.x;
  const int lane = tid & 63, w = tid >> 6;
  const int quad = lane >> 4, l15 = lane & 15;
  const int qt = blockIdx.x, hh = blockIdx.y, b = blockIdx.z;
  const int dh = hh * 64;
  const size_t qrow0 = (size_t)b * kS + (size_t)qt * 64;
  const u16* __restrict__ vbase = VTg + ((size_t)(b * 16 + hh) * 64) * kS;

#pragma unroll
  for (int e = 0; e < 4; ++e) {                  // stage Q (bf16, 8 KB)
    int flat = tid + e * 256;                    // 0..1023 (ushort4 units)
    int row = flat >> 4, d4 = (flat & 15) * 4;
    *(ushort4*)&Qs[row * 72 + d4] =
        *(const ushort4*)&Qb[(qrow0 + row) * kD + dh + d4];
  }

  float m[4], l[4];
  f32x4 O[4];
#pragma unroll
  for (int i = 0; i < 4; ++i) { m[i] = -INFINITY; l[i] = 0.f; }
#pragma unroll
  for (int nt = 0; nt < 4; ++nt) O[nt] = {0.f, 0.f, 0.f, 0.f};

#pragma unroll 1
  for (int kt = 0; kt <= qt; ++kt) {
    const size_t krow0 = (size_t)b * kS + (size_t)kt * 64;
    __syncthreads();                             // prior-iter readers done (covers Q on iter 0)
#pragma unroll
    for (int e = 0; e < 4; ++e) {                // stage K and V^T
      int flat = tid + e * 256;
      int row = flat >> 4, d4 = (flat & 15) * 4;
      *(ushort4*)&Ks[row * 72 + d4] =
          *(const ushort4*)&Kb[(krow0 + row) * kD + dh + d4];
      *(ushort4*)&VTs[row * 72 + d4] =
          *(const ushort4*)&vbase[(size_t)row * kS + kt * 64 + d4];
    }
    __syncthreads();

    // ---- S = Q K^T (raw; 1/8 scale folded into exp args) ----
    s8v aq0 = *(const s8v*)&Qs[(w * 16 + l15) * 72 + quad * 8];
    s8v aq1 = *(const s8v*)&Qs[(w * 16 + l15) * 72 + 32 + quad * 8];
    f32x4 s[4];
#pragma unroll
    for (int nt = 0; nt < 4; ++nt) {
      s8v bk0 = *(const s8v*)&Ks[(nt * 16 + l15) * 72 + quad * 8];
      s8v bk1 = *(const s8v*)&Ks[(nt * 16 + l15) * 72 + 32 + quad * 8];
      f32x4 z = {0.f, 0.f, 0.f, 0.f};
      z = __builtin_amdgcn_mfma_f32_16x16x32_bf16(aq0, bk0, z, 0, 0, 0);
      s[nt] = __builtin_amdgcn_mfma_f32_16x16x32_bf16(aq1, bk1, z, 0, 0, 0);
    }

    if (kt == qt) {                              // causal mask (diagonal tile)
#pragma unroll
      for (int nt = 0; nt < 4; ++nt)
#pragma unroll
        for (int i = 0; i < 4; ++i)
          if (nt * 16 + l15 > w * 16 + quad * 4 + i) s[nt][i] = -1e30f;
    }

    // ---- online softmax (rows = quad*4+i; cols spread over 16 lanes) ----
    float alpha[4];
#pragma unroll
    for (int i = 0; i < 4; ++i) {
      float pm = fmaxf(fmaxf(s[0][i], s[1][i]), fmaxf(s[2][i], s[3][i]));
#pragma unroll
      for (int off = 1; off < 16; off <<= 1)
        pm = fmaxf(pm, __shfl_xor(pm, off, 64));
      float mn = fmaxf(m[i], pm);
      alpha[i] = __expf((m[i] - mn) * 0.125f);
      m[i] = mn;
      float p0 = __expf((s[0][i] - mn) * 0.125f);
      float p1 = __expf((s[1][i] - mn) * 0.125f);
      float p2 = __expf((s[2][i] - mn) * 0.125f);
      float p3 = __expf((s[3][i] - mn) * 0.125f);
      float r = p0 + p1 + p2 + p3;
#pragma unroll
      for (int off = 1; off < 16; off <<= 1)
        r += __shfl_xor(r, off, 64);
      l[i] = l[i] * alpha[i] + r;
      short* pw = &Ps[w][(quad * 4 + i) * 72 + l15];
      pw[0]  = (short)f2bf_bits(p0);
      pw[16] = (short)f2bf_bits(p1);
      pw[32] = (short)f2bf_bits(p2);
      pw[48] = (short)f2bf_bits(p3);
    }
#pragma unroll
    for (int nt = 0; nt < 4; ++nt)
#pragma unroll
      for (int i = 0; i < 4; ++i) O[nt][i] *= alpha[i];

    // ---- O += P V  (P from per-wave LDS strip in A-layout) ----
    s8v ap0 = *(const s8v*)&Ps[w][l15 * 72 + quad * 8];
    s8v ap1 = *(const s8v*)&Ps[w][l15 * 72 + 32 + quad * 8];
#pragma unroll
    for (int nt = 0; nt < 4; ++nt) {
      s8v bv0 = *(const s8v*)&VTs[(nt * 16 + l15) * 72 + quad * 8];
      s8v bv1 = *(const s8v*)&VTs[(nt * 16 + l15) * 72 + 32 + quad * 8];
      O[nt] = __builtin_amdgcn_mfma_f32_16x16x32_bf16(ap0, bv0, O[nt], 0, 0, 0);
      O[nt] = __builtin_amdgcn_mfma_f32_16x16x32_bf16(ap1, bv1, O[nt], 0, 0, 0);
    }
  }

#pragma unroll
  for (int i = 0; i < 4; ++i) {
    float inv = 1.f / l[i];
    size_t row = qrow0 + w * 16 + quad * 4 + i;
#pragma unroll
    for (int nt = 0; nt < 4; ++nt)
      AOb[row * kD + dh + nt * 16 + l15] = f2bf_bits(O[nt][i] * inv);
  }
}

// ---------------------------------------------------------------------------
// WO-GEMM: out[t][d] = sum_e AO[t][e] * W_O[d][e].  W_O is already B^T layout.
// ---------------------------------------------------------------------------
__global__ __launch_bounds__(256) void wo_gemm(const u16* __restrict__ AOb,
                                               const float* __restrict__ WO,
                                               float* __restrict__ out) {
  __shared__ short As[128 * 40];
  __shared__ short Bs[128 * 40];
  const int tid = threadIdx.x;
  const int lane = tid & 63, wid = tid >> 6;
  const int wm = wid & 1, wn = wid >> 1;
  const int quad = lane >> 4, l15 = lane & 15;
  const int dT = blockIdx.x * 128;
  const int tok0 = blockIdx.y * 128;

  f32x4 acc[4][4];
#pragma unroll
  for (int mt = 0; mt < 4; ++mt)
#pragma unroll
    for (int nt = 0; nt < 4; ++nt) acc[mt][nt] = {0.f, 0.f, 0.f, 0.f};

#pragma unroll 1
  for (int e0 = 0; e0 < kD; e0 += 32) {
    __syncthreads();
#pragma unroll
    for (int e = 0; e < 2; ++e) {                 // A: AO bf16 direct
      int flat = tid + e * 256;                   // 0..511 (16B units, 4/row)
      int row = flat >> 2, kq = (flat & 3) * 8;
      *(s8v*)&As[row * 40 + kq] =
          *(const s8v*)&AOb[(size_t)(tok0 + row) * kD + e0 + kq];
    }
#pragma unroll
    for (int e = 0; e < 4; ++e) {                 // B: W_O fp32 -> bf16
      int flat = tid + e * 256;                   // 0..1023 (float4 units)
      int col = flat >> 3, kq = (flat & 7) * 4;
      float4 v = *(const float4*)&WO[(size_t)(dT + col) * kD + e0 + kq];
      uint2 o = { pk_bf16(v.x, v.y), pk_bf16(v.z, v.w) };
      *(uint2*)&Bs[col * 40 + kq] = o;
    }
    __syncthreads();
    s8v a[4], b[4];
#pragma unroll
    for (int mt = 0; mt < 4; ++mt)
      a[mt] = *(const s8v*)&As[(wm * 64 + mt * 16 + l15) * 40 + quad * 8];
#pragma unroll
    for (int nt = 0; nt < 4; ++nt)
      b[nt] = *(const s8v*)&Bs[(wn * 64 + nt * 16 + l15) * 40 + quad * 8];
#pragma unroll
    for (int mt = 0; mt < 4; ++mt)
#pragma unroll
      for (int nt = 0; nt < 4; ++nt)
        acc[mt][nt] = __builtin_amdgcn_mfma_f32_16x16x32_bf16(
            a[mt], b[nt], acc[mt][nt], 0, 0, 0);
  }
#pragma unroll
  for (int mt = 0; mt < 4; ++mt)
#pragma unroll
    for (int nt = 0; nt < 4; ++nt) {
      int col = dT + wn * 64 + nt * 16 + l15;
      int rbase = tok0 + wm * 64 + mt * 16 + quad * 4;
#pragma unroll
      for (int i = 0; i < 4; ++i)
        out[(size_t)(rbase + i) * kD + col] = acc[mt][nt][i];
    }
}

// ---------------------------------------------------------------------------
extern "C" void kernel_launch(void* const* d_in, const int* in_sizes, int n_in,
                              void* d_out, int out_size, void* d_ws, size_t ws_size,
                              hipStream_t stream) {
  const float* x     = (const float*)d_in[0];
  const float* fqk_w = (const float*)d_in[1];
  const float* fv_w  = (const float*)d_in[2];
  const float* wq    = (const float*)d_in[3];
  const float* wk    = (const float*)d_in[4];
  const float* wv    = (const float*)d_in[5];
  const float* f_neu = (const float*)d_in[6];
  const float* r_neu = (const float*)d_in[7];
  const float* WO    = (const float*)d_in[8];
  float* out = (float*)d_out;

  // ws layout (96 MB used, lifetime-overlapped):
  //  [0,8)   FT (dead after g_gemm)
  //  [8,16)  RT (dead after qkv_gemm)
  //  [16,80) G  (dead after reduce_h) -> Qb [16,32), Kb [32,48), VTg [48,64),
  //                                      AOb [64,80)
  //  [80,84) h_qk, h_v
  char* ws = (char*)d_ws;
  u16*   FT   = (u16*)  (ws);
  u16*   RT   = (u16*)  (ws + ((size_t)8u  << 20));
  u16*   G    = (u16*)  (ws + ((size_t)16u << 20));
  float* h_qk = (float*)(ws + ((size_t)80u << 20));
  float* h_v  = (float*)(ws + ((size_t)82u << 20));
  u16*   Qb   = (u16*)  (ws + ((size_t)16u << 20));
  u16*   Kb   = (u16*)  (ws + ((size_t)32u << 20));
  u16*   VTg  = (u16*)  (ws + ((size_t)48u << 20));
  u16*   AOb  = (u16*)  (ws + ((size_t)64u << 20));

  hipLaunchKernelGGL(t1_kernel, dim3(8, 64), dim3(256), 0, stream, f_neu, FT);
  hipLaunchKernelGGL(t2_kernel, dim3(8, 64), dim3(256), 0, stream, r_neu, RT);
  hipLaunchKernelGGL(g_gemm, dim3(32, 64), dim3(256), 0, stream, x, FT, G);
  hipLaunchKernelGGL(reduce_h, dim3(512), dim3(256), 0, stream,
                     G, fqk_w, fv_w, h_qk, h_v);
  hipLaunchKernelGGL(qkv_gemm, dim3(8, 64, 3), dim3(256), 0, stream,
                     h_qk, h_v, wq, wk, wv, RT, Qb, Kb, VTg);
  hipLaunchKernelGGL(attn_mfma, dim3(32, 16, 4), dim3(256), 0, stream,
                     Qb, Kb, VTg, AOb);
  hipLaunchKernelGGL(wo_gemm, dim3(8, 64), dim3(256), 0, stream,
                     AOb, WO, out);
}

// Round 5
// 634.132 us; speedup vs baseline: 6.9127x; 1.1042x over previous
//
#include <hip/hip_runtime.h>
#include <hip/hip_bf16.h>

// AttentionCircuit round 5:
//  - attn: 128-row Q tile, 512-thread (8-wave) blocks, register prefetch of
//    next K/V tile to hide global latency across the barrier.
//  - g/qkv/wo GEMMs: BK=64 (half the barriers, 32 MFMA per barrier pair).

namespace {
constexpr int kS = 2048;
constexpr int kD = 1024;
}

typedef unsigned short u16;
typedef __attribute__((ext_vector_type(4))) float f32x4;
typedef __attribute__((ext_vector_type(8))) short s8v;   // 8 bf16 = 4 VGPRs

union FragU { s8v s; unsigned u[4]; };

__device__ __forceinline__ u16 f2bf_bits(float f) {
  union { float f; unsigned u; } cv; cv.f = f;
  unsigned u = cv.u;
  unsigned r = u + 0x7fffu + ((u >> 16) & 1u);   // RNE
  return (u16)(r >> 16);
}
__device__ __forceinline__ float bf2f(u16 b) {
  union { unsigned u; float f; } cv; cv.u = ((unsigned)b) << 16; return cv.f;
}
__device__ __forceinline__ unsigned pk_bf16(float a, float b) {
  __hip_bfloat162 h = __float22bfloat162_rn(make_float2(a, b));
  union { __hip_bfloat162 h; unsigned u; } cv; cv.h = h; return cv.u;
}

// ---------------------------------------------------------------------------
// T1: FT[n*64+r][d] = f[n][d][r]  (bf16)  — B^T layout for G-GEMM.
// ---------------------------------------------------------------------------
__global__ __launch_bounds__(256) void t1_kernel(const float* __restrict__ f,
                                                 u16* __restrict__ FT) {
  __shared__ float Tt[64 * 132];
  const int tid = threadIdx.x;
  const int d0 = blockIdx.x * 128;
  const int n  = blockIdx.y;
#pragma unroll
  for (int e = 0; e < 8; ++e) {
    int flat = tid + e * 256;            // 0..2047
    int dd = flat >> 4, r4 = (flat & 15) * 4;
    float4 v = *(const float4*)&f[((size_t)n * kD + d0 + dd) * 64 + r4];
    Tt[(r4 + 0) * 132 + dd] = v.x;
    Tt[(r4 + 1) * 132 + dd] = v.y;
    Tt[(r4 + 2) * 132 + dd] = v.z;
    Tt[(r4 + 3) * 132 + dd] = v.w;
  }
  __syncthreads();
#pragma unroll
  for (int e = 0; e < 4; ++e) {
    int flat = tid + e * 256;            // 0..1023
    int r = flat >> 4, dq = (flat & 15) * 8;
    const float* p = &Tt[r * 132 + dq];
    uint4 o = { pk_bf16(p[0], p[1]), pk_bf16(p[2], p[3]),
                pk_bf16(p[4], p[5]), pk_bf16(p[6], p[7]) };
    *(uint4*)&FT[((size_t)n * 64 + r) * kD + d0 + dq] = o;
  }
}

// ---------------------------------------------------------------------------
// T2: RT[d][n*64+r] = r_neurons[n][r][d] (bf16) — B^T layout for QKV GEMM.
// ---------------------------------------------------------------------------
__global__ __launch_bounds__(256) void t2_kernel(const float* __restrict__ rn,
                                                 u16* __restrict__ RT) {
  __shared__ float Tt[128 * 68];
  const int tid = threadIdx.x;
  const int d0 = blockIdx.x * 128;
  const int n  = blockIdx.y;             // 0..63
#pragma unroll
  for (int e = 0; e < 8; ++e) {
    int flat = tid + e * 256;            // 0..2047
    int r = flat >> 5, d4 = (flat & 31) * 4;
    float4 v = *(const float4*)&rn[((size_t)n * 64 + r) * kD + d0 + d4];
    Tt[(d4 + 0) * 68 + r] = v.x;
    Tt[(d4 + 1) * 68 + r] = v.y;
    Tt[(d4 + 2) * 68 + r] = v.z;
    Tt[(d4 + 3) * 68 + r] = v.w;
  }
  __syncthreads();
#pragma unroll
  for (int e = 0; e < 4; ++e) {
    int flat = tid + e * 256;            // 0..1023
    int dd = flat >> 3, rq = (flat & 7) * 8;
    const float* p = &Tt[dd * 68 + rq];
    uint4 o = { pk_bf16(p[0], p[1]), pk_bf16(p[2], p[3]),
                pk_bf16(p[4], p[5]), pk_bf16(p[6], p[7]) };
    *(uint4*)&RT[((size_t)(d0 + dd)) * 4096 + n * 64 + rq] = o;
  }
}

// ---------------------------------------------------------------------------
// G-GEMM: G[t][g] = sum_d bf16(x[t,d]) * FT[g][d].  M=8192 K=1024 N=4096.
// 128x128 tile, BK=64, 16 iterations, 32 MFMA per barrier pair.
// ---------------------------------------------------------------------------
__global__ __launch_bounds__(256) void g_gemm(const float* __restrict__ x,
                                              const u16* __restrict__ FT,
                                              u16* __restrict__ G) {
  __shared__ short As[128 * 72];
  __shared__ short Bs[128 * 72];
  const int tid = threadIdx.x;
  const int lane = tid & 63, wid = tid >> 6;
  const int wm = wid & 1, wn = wid >> 1;
  const int quad = lane >> 4, l15 = lane & 15;
  const int cT = blockIdx.x * 128;
  const int tok0 = blockIdx.y * 128;

  f32x4 acc[4][4];
#pragma unroll
  for (int mt = 0; mt < 4; ++mt)
#pragma unroll
    for (int nt = 0; nt < 4; ++nt) acc[mt][nt] = {0.f, 0.f, 0.f, 0.f};

#pragma unroll 1
  for (int d0 = 0; d0 < kD; d0 += 64) {
    __syncthreads();
#pragma unroll
    for (int e = 0; e < 8; ++e) {                 // A: x fp32 -> bf16, 128x64
      int flat = tid + e * 256;                   // 0..2047 (float4 units)
      int row = flat >> 4, kq = (flat & 15) * 4;
      float4 v = *(const float4*)&x[(size_t)(tok0 + row) * kD + d0 + kq];
      uint2 o = { pk_bf16(v.x, v.y), pk_bf16(v.z, v.w) };
      *(uint2*)&As[row * 72 + kq] = o;
    }
#pragma unroll
    for (int e = 0; e < 4; ++e) {                 // B: FT bf16 direct, 128x64
      int flat = tid + e * 256;                   // 0..1023 (16B units, 8/row)
      int col = flat >> 3, kq = (flat & 7) * 8;
      *(s8v*)&Bs[col * 72 + kq] =
          *(const s8v*)&FT[(size_t)(cT + col) * kD + d0 + kq];
    }
    __syncthreads();
    s8v a0[4], a1[4], b0[4], b1[4];
#pragma unroll
    for (int mt = 0; mt < 4; ++mt) {
      const short* p = &As[(wm * 64 + mt * 16 + l15) * 72 + quad * 8];
      a0[mt] = *(const s8v*)p;
      a1[mt] = *(const s8v*)(p + 32);
    }
#pragma unroll
    for (int nt = 0; nt < 4; ++nt) {
      const short* p = &Bs[(wn * 64 + nt * 16 + l15) * 72 + quad * 8];
      b0[nt] = *(const s8v*)p;
      b1[nt] = *(const s8v*)(p + 32);
    }
#pragma unroll
    for (int mt = 0; mt < 4; ++mt)
#pragma unroll
      for (int nt = 0; nt < 4; ++nt) {
        acc[mt][nt] = __builtin_amdgcn_mfma_f32_16x16x32_bf16(
            a0[mt], b0[nt], acc[mt][nt], 0, 0, 0);
        acc[mt][nt] = __builtin_amdgcn_mfma_f32_16x16x32_bf16(
            a1[mt], b1[nt], acc[mt][nt], 0, 0, 0);
      }
  }
#pragma unroll
  for (int mt = 0; mt < 4; ++mt)
#pragma unroll
    for (int nt = 0; nt < 4; ++nt) {
      int col = cT + wn * 64 + nt * 16 + l15;
      int rbase = tok0 + wm * 64 + mt * 16 + quad * 4;
#pragma unroll
      for (int i = 0; i < 4; ++i)
        G[(size_t)(rbase + i) * 4096 + col] = f2bf_bits(acc[mt][nt][i]);
    }
}

// ---------------------------------------------------------------------------
// reduce_h: h_qk[t][r] = sum_n fqk_w[t][n]*G[t][n*64+r]; h_v from cols 2048+.
// ---------------------------------------------------------------------------
__global__ __launch_bounds__(256) void reduce_h(const u16* __restrict__ G,
                                                const float* __restrict__ fqk_w,
                                                const float* __restrict__ fv_w,
                                                float* __restrict__ h_qk,
                                                float* __restrict__ h_v) {
  int idx = blockIdx.x * 256 + threadIdx.x;    // 0..131071
  int t = idx >> 4, r4 = (idx & 15) * 4;
  float4 aq = {0.f, 0.f, 0.f, 0.f}, av = {0.f, 0.f, 0.f, 0.f};
  const u16* gq = &G[(size_t)t * 4096 + r4];
  const u16* gv = gq + 2048;
#pragma unroll 4
  for (int n = 0; n < 32; ++n) {
    float wa = fqk_w[t * 32 + n];
    float wb = fv_w[t * 32 + n];
    ushort4 g1 = *(const ushort4*)&gq[n * 64];
    ushort4 g2 = *(const ushort4*)&gv[n * 64];
    aq.x += wa * bf2f(g1.x); aq.y += wa * bf2f(g1.y);
    aq.z += wa * bf2f(g1.z); aq.w += wa * bf2f(g1.w);
    av.x += wb * bf2f(g2.x); av.y += wb * bf2f(g2.y);
    av.z += wb * bf2f(g2.z); av.w += wb * bf2f(g2.w);
  }
  *(float4*)&h_qk[t * 64 + r4] = aq;
  *(float4*)&h_v[t * 64 + r4] = av;
}

// ---------------------------------------------------------------------------
// QKV-GEMM: C[t][d] = sum_g (w[t,n]*h[t,r]) * RT[d][g0+g],  g=n*64+r, K=2048.
// n-loop of 32 iterations, 64-wide k slab (r=0..63) per barrier pair.
// which: 0->Qb (bf16, [t][d]), 1->Kb (bf16, [t][d]), 2->VTg ([b][h][d][s]).
// ---------------------------------------------------------------------------
__global__ __launch_bounds__(256) void qkv_gemm(
    const float* __restrict__ h_qk, const float* __restrict__ h_v,
    const float* __restrict__ wq, const float* __restrict__ wk,
    const float* __restrict__ wv, const u16* __restrict__ RT,
    u16* __restrict__ Qb, u16* __restrict__ Kb, u16* __restrict__ VTg) {
  __shared__ float hs[128 * 68];
  __shared__ float wsl[128 * 33];
  __shared__ short Bs[128 * 72];
  const int tid = threadIdx.x;
  const int lane = tid & 63, wid = tid >> 6;
  const int wm = wid & 1, wn = wid >> 1;
  const int quad = lane >> 4, l15 = lane & 15;
  const int dT = blockIdx.x * 128;
  const int tok0 = blockIdx.y * 128;
  const int which = blockIdx.z;
  const float* __restrict__ h = (which == 2) ? h_v : h_qk;
  const float* __restrict__ w = (which == 0) ? wq : (which == 1) ? wk : wv;
  const int g0 = (which == 2) ? 2048 : 0;

#pragma unroll
  for (int e = 0; e < 8; ++e) {                  // h tile: 128x64 fp32
    int flat = tid + e * 256;                    // 0..2047 (float4 units)
    int row = flat >> 4, rq = (flat & 15) * 4;
    *(float4*)&hs[row * 68 + rq] =
        *(const float4*)&h[(size_t)(tok0 + row) * 64 + rq];
  }
#pragma unroll
  for (int e = 0; e < 16; ++e) {                 // w tile: 128x32 fp32
    int flat = tid + e * 256;                    // 0..4095
    int row = flat >> 5, nn = flat & 31;
    wsl[row * 33 + nn] = w[(size_t)(tok0 + row) * 32 + nn];
  }

  f32x4 acc[4][4];
#pragma unroll
  for (int mt = 0; mt < 4; ++mt)
#pragma unroll
    for (int nt = 0; nt < 4; ++nt) acc[mt][nt] = {0.f, 0.f, 0.f, 0.f};

#pragma unroll 1
  for (int n = 0; n < 32; ++n) {
    __syncthreads();
#pragma unroll
    for (int e = 0; e < 4; ++e) {                // B: 128 cols x 64 k
      int flat = tid + e * 256;                  // 0..1023 (16B units, 8/row)
      int col = flat >> 3, kq = (flat & 7) * 8;
      *(s8v*)&Bs[col * 72 + kq] =
          *(const s8v*)&RT[(size_t)(dT + col) * 4096 + g0 + n * 64 + kq];
    }
    __syncthreads();
    s8v a0[4], a1[4], b0[4], b1[4];
#pragma unroll
    for (int mt = 0; mt < 4; ++mt) {
      int row = wm * 64 + mt * 16 + l15;
      float wv_ = wsl[row * 33 + n];
      const float* hp = &hs[row * 68 + quad * 8];
      FragU fa, fb;
      fa.u[0] = pk_bf16(wv_ * hp[0], wv_ * hp[1]);
      fa.u[1] = pk_bf16(wv_ * hp[2], wv_ * hp[3]);
      fa.u[2] = pk_bf16(wv_ * hp[4], wv_ * hp[5]);
      fa.u[3] = pk_bf16(wv_ * hp[6], wv_ * hp[7]);
      a0[mt] = fa.s;
      fb.u[0] = pk_bf16(wv_ * hp[32], wv_ * hp[33]);
      fb.u[1] = pk_bf16(wv_ * hp[34], wv_ * hp[35]);
      fb.u[2] = pk_bf16(wv_ * hp[36], wv_ * hp[37]);
      fb.u[3] = pk_bf16(wv_ * hp[38], wv_ * hp[39]);
      a1[mt] = fb.s;
    }
#pragma unroll
    for (int nt = 0; nt < 4; ++nt) {
      const short* p = &Bs[(wn * 64 + nt * 16 + l15) * 72 + quad * 8];
      b0[nt] = *(const s8v*)p;
      b1[nt] = *(const s8v*)(p + 32);
    }
#pragma unroll
    for (int mt = 0; mt < 4; ++mt)
#pragma unroll
      for (int nt = 0; nt < 4; ++nt) {
        acc[mt][nt] = __builtin_amdgcn_mfma_f32_16x16x32_bf16(
            a0[mt], b0[nt], acc[mt][nt], 0, 0, 0);
        acc[mt][nt] = __builtin_amdgcn_mfma_f32_16x16x32_bf16(
            a1[mt], b1[nt], acc[mt][nt], 0, 0, 0);
      }
  }

  if (which < 2) {
    u16* __restrict__ O = (which == 0) ? Qb : Kb;
#pragma unroll
    for (int mt = 0; mt < 4; ++mt)
#pragma unroll
      for (int nt = 0; nt < 4; ++nt) {
        int col = dT + wn * 64 + nt * 16 + l15;
        int rbase = tok0 + wm * 64 + mt * 16 + quad * 4;
#pragma unroll
        for (int i = 0; i < 4; ++i)
          O[(size_t)(rbase + i) * kD + col] = f2bf_bits(acc[mt][nt][i]);
      }
  } else {
#pragma unroll
    for (int mt = 0; mt < 4; ++mt)
#pragma unroll
      for (int nt = 0; nt < 4; ++nt) {
        int d = dT + wn * 64 + nt * 16 + l15;
        int hh = d >> 6, dl = d & 63;
        int t = tok0 + wm * 64 + mt * 16 + quad * 4;   // 4 consecutive tokens
        int bb = t >> 11, sl = t & 2047;
        ushort4 u = { f2bf_bits(acc[mt][nt][0]), f2bf_bits(acc[mt][nt][1]),
                      f2bf_bits(acc[mt][nt][2]), f2bf_bits(acc[mt][nt][3]) };
        *(ushort4*)&VTg[(((size_t)bb * 16 + hh) * 64 + dl) * kS + sl] = u;
      }
  }
}

// ---------------------------------------------------------------------------
// Flash attention, MFMA. Block = (qb, head, batch): 128 q-rows, 512 threads
// (8 waves, wave w owns rows w*16..w*16+15). K/V tiles 64 tokens, register
// prefetch of tile kt+1 issued before computing tile kt.
// ---------------------------------------------------------------------------
__global__ __launch_bounds__(512) void attn_mfma(
    const u16* __restrict__ Qb, const u16* __restrict__ Kb,
    const u16* __restrict__ VTg, u16* __restrict__ AOb)
{
  __shared__ short Qs[128 * 72];      // [q-row][d]
  __shared__ short Ks[64 * 72];       // [k-tok][d]
  __shared__ short VTs[64 * 72];      // [d][k-tok]
  __shared__ short Ps[8][16 * 72];    // per-wave P strip [q-row-local][k-tok]
  const int tid = threadIdx.x;
  const int lane = tid & 63, w = tid >> 6;       // w 0..7
  const int quad = lane >> 4, l15 = lane & 15;
  const int qb = blockIdx.x, hh = blockIdx.y, b = blockIdx.z;
  const int dh = hh * 64;
  const size_t qrow0 = (size_t)b * kS + (size_t)qb * 128;
  const int ktmax = qb * 2 + 1;
  const u16* __restrict__ vbase = VTg + ((size_t)(b * 16 + hh) * 64) * kS;

  // stage Q (128x64 bf16) and K/V tile 0
  {
    const int row0 = tid >> 4, d4 = (tid & 15) * 4;
#pragma unroll
    for (int e = 0; e < 4; ++e) {
      int row = row0 + e * 32;                   // 0..127
      *(ushort4*)&Qs[row * 72 + d4] =
          *(const ushort4*)&Qb[(qrow0 + row) * kD + dh + d4];
    }
#pragma unroll
    for (int e = 0; e < 2; ++e) {
      int row = row0 + e * 32;                   // 0..63
      *(ushort4*)&Ks[row * 72 + d4] =
          *(const ushort4*)&Kb[((size_t)b * kS + row) * kD + dh + d4];
      *(ushort4*)&VTs[row * 72 + d4] =
          *(const ushort4*)&vbase[(size_t)row * kS + d4];
    }
  }
  __syncthreads();

  // loop-invariant Q fragments for this wave's 16 rows
  s8v aq0 = *(const s8v*)&Qs[(w * 16 + l15) * 72 + quad * 8];
  s8v aq1 = *(const s8v*)&Qs[(w * 16 + l15) * 72 + 32 + quad * 8];

  float m[4], l[4];
  f32x4 O[4];
#pragma unroll
  for (int i = 0; i < 4; ++i) { m[i] = -INFINITY; l[i] = 0.f; }
#pragma unroll
  for (int nt = 0; nt < 4; ++nt) O[nt] = {0.f, 0.f, 0.f, 0.f};

  const int prow = tid >> 4, pd4 = (tid & 15) * 4;   // prefetch lane mapping

#pragma unroll 1
  for (int kt = 0; kt <= ktmax; ++kt) {
    // ---- issue prefetch of tile kt+1 (latency hidden under compute) ----
    ushort4 pk0, pk1, pv0, pv1;
    if (kt < ktmax) {
      const size_t krow0n = (size_t)b * kS + (size_t)(kt + 1) * 64;
      pk0 = *(const ushort4*)&Kb[(krow0n + prow) * kD + dh + pd4];
      pk1 = *(const ushort4*)&Kb[(krow0n + prow + 32) * kD + dh + pd4];
      pv0 = *(const ushort4*)&vbase[(size_t)prow * kS + (kt + 1) * 64 + pd4];
      pv1 = *(const ushort4*)&vbase[(size_t)(prow + 32) * kS + (kt + 1) * 64 + pd4];
    }

    // ---- S = Q K^T (raw; 1/8 folded into exp args) ----
    f32x4 s[4];
#pragma unroll
    for (int nt = 0; nt < 4; ++nt) {
      const short* p = &Ks[(nt * 16 + l15) * 72 + quad * 8];
      s8v bk0 = *(const s8v*)p;
      s8v bk1 = *(const s8v*)(p + 32);
      f32x4 z = {0.f, 0.f, 0.f, 0.f};
      z = __builtin_amdgcn_mfma_f32_16x16x32_bf16(aq0, bk0, z, 0, 0, 0);
      s[nt] = __builtin_amdgcn_mfma_f32_16x16x32_bf16(aq1, bk1, z, 0, 0, 0);
    }

    if (kt * 64 + 63 > qb * 128 + w * 16) {      // causal mask possible
#pragma unroll
      for (int nt = 0; nt < 4; ++nt)
#pragma unroll
        for (int i = 0; i < 4; ++i)
          if (kt * 64 + nt * 16 + l15 > qb * 128 + w * 16 + quad * 4 + i)
            s[nt][i] = -1e30f;
    }

    // ---- online softmax (rows i; cols over 16 lanes x 4 nt) ----
    float alpha[4];
#pragma unroll
    for (int i = 0; i < 4; ++i) {
      float pm = fmaxf(fmaxf(s[0][i], s[1][i]), fmaxf(s[2][i], s[3][i]));
#pragma unroll
      for (int off = 1; off < 16; off <<= 1)
        pm = fmaxf(pm, __shfl_xor(pm, off, 64));
      float mn = fmaxf(m[i], pm);
      alpha[i] = __expf((m[i] - mn) * 0.125f);
      m[i] = mn;
      float p0 = __expf((s[0][i] - mn) * 0.125f);
      float p1 = __expf((s[1][i] - mn) * 0.125f);
      float p2 = __expf((s[2][i] - mn) * 0.125f);
      float p3 = __expf((s[3][i] - mn) * 0.125f);
      float r = p0 + p1 + p2 + p3;
#pragma unroll
      for (int off = 1; off < 16; off <<= 1)
        r += __shfl_xor(r, off, 64);
      l[i] = l[i] * alpha[i] + r;
      short* pw = &Ps[w][(quad * 4 + i) * 72 + l15];
      pw[0]  = (short)f2bf_bits(p0);
      pw[16] = (short)f2bf_bits(p1);
      pw[32] = (short)f2bf_bits(p2);
      pw[48] = (short)f2bf_bits(p3);
    }
#pragma unroll
    for (int nt = 0; nt < 4; ++nt)
#pragma unroll
      for (int i = 0; i < 4; ++i) O[nt][i] *= alpha[i];

    // ---- O += P V (P strip -> A layout; V^T tile -> B layout) ----
    s8v ap0 = *(const s8v*)&Ps[w][l15 * 72 + quad * 8];
    s8v ap1 = *(const s8v*)&Ps[w][l15 * 72 + 32 + quad * 8];
#pragma unroll
    for (int nt = 0; nt < 4; ++nt) {
      const short* p = &VTs[(nt * 16 + l15) * 72 + quad * 8];
      s8v bv0 = *(const s8v*)p;
      s8v bv1 = *(const s8v*)(p + 32);
      O[nt] = __builtin_amdgcn_mfma_f32_16x16x32_bf16(ap0, bv0, O[nt], 0, 0, 0);
      O[nt] = __builtin_amdgcn_mfma_f32_16x16x32_bf16(ap1, bv1, O[nt], 0, 0, 0);
    }

    __syncthreads();                             // all reads of Ks/VTs done
    if (kt < ktmax) {                            // commit prefetched tile
      *(ushort4*)&Ks[prow * 72 + pd4] = pk0;
      *(ushort4*)&Ks[(prow + 32) * 72 + pd4] = pk1;
      *(ushort4*)&VTs[prow * 72 + pd4] = pv0;
      *(ushort4*)&VTs[(prow + 32) * 72 + pd4] = pv1;
    }
    __syncthreads();
  }

#pragma unroll
  for (int i = 0; i < 4; ++i) {
    float inv = 1.f / l[i];
    size_t row = qrow0 + w * 16 + quad * 4 + i;
#pragma unroll
    for (int nt = 0; nt < 4; ++nt)
      AOb[row * kD + dh + nt * 16 + l15] = f2bf_bits(O[nt][i] * inv);
  }
}

// ---------------------------------------------------------------------------
// WO-GEMM: out[t][d] = sum_e AO[t][e] * W_O[d][e].  BK=64.
// ---------------------------------------------------------------------------
__global__ __launch_bounds__(256) void wo_gemm(const u16* __restrict__ AOb,
                                               const float* __restrict__ WO,
                                               float* __restrict__ out) {
  __shared__ short As[128 * 72];
  __shared__ short Bs[128 * 72];
  const int tid = threadIdx.x;
  const int lane = tid & 63, wid = tid >> 6;
  const int wm = wid & 1, wn = wid >> 1;
  const int quad = lane >> 4, l15 = lane & 15;
  const int dT = blockIdx.x * 128;
  const int tok0 = blockIdx.y * 128;

  f32x4 acc[4][4];
#pragma unroll
  for (int mt = 0; mt < 4; ++mt)
#pragma unroll
    for (int nt = 0; nt < 4; ++nt) acc[mt][nt] = {0.f, 0.f, 0.f, 0.f};

#pragma unroll 1
  for (int e0 = 0; e0 < kD; e0 += 64) {
    __syncthreads();
#pragma unroll
    for (int e = 0; e < 4; ++e) {                 // A: AO bf16 direct, 128x64
      int flat = tid + e * 256;                   // 0..1023 (16B units, 8/row)
      int row = flat >> 3, kq = (flat & 7) * 8;
      *(s8v*)&As[row * 72 + kq] =
          *(const s8v*)&AOb[(size_t)(tok0 + row) * kD + e0 + kq];
    }
#pragma unroll
    for (int e = 0; e < 8; ++e) {                 // B: W_O fp32 -> bf16
      int flat = tid + e * 256;                   // 0..2047 (float4 units)
      int col = flat >> 4, kq = (flat & 15) * 4;
      float4 v = *(const float4*)&WO[(size_t)(dT + col) * kD + e0 + kq];
      uint2 o = { pk_bf16(v.x, v.y), pk_bf16(v.z, v.w) };
      *(uint2*)&Bs[col * 72 + kq] = o;
    }
    __syncthreads();
    s8v a0[4], a1[4], b0[4], b1[4];
#pragma unroll
    for (int mt = 0; mt < 4; ++mt) {
      const short* p = &As[(wm * 64 + mt * 16 + l15) * 72 + quad * 8];
      a0[mt] = *(const s8v*)p;
      a1[mt] = *(const s8v*)(p + 32);
    }
#pragma unroll
    for (int nt = 0; nt < 4; ++nt) {
      const short* p = &Bs[(wn * 64 + nt * 16 + l15) * 72 + quad * 8];
      b0[nt] = *(const s8v*)p;
      b1[nt] = *(const s8v*)(p + 32);
    }
#pragma unroll
    for (int mt = 0; mt < 4; ++mt)
#pragma unroll
      for (int nt = 0; nt < 4; ++nt) {
        acc[mt][nt] = __builtin_amdgcn_mfma_f32_16x16x32_bf16(
            a0[mt], b0[nt], acc[mt][nt], 0, 0, 0);
        acc[mt][nt] = __builtin_amdgcn_mfma_f32_16x16x32_bf16(
            a1[mt], b1[nt], acc[mt][nt], 0, 0, 0);
      }
  }
#pragma unroll
  for (int mt = 0; mt < 4; ++mt)
#pragma unroll
    for (int nt = 0; nt < 4; ++nt) {
      int col = dT + wn * 64 + nt * 16 + l15;
      int rbase = tok0 + wm * 64 + mt * 16 + quad * 4;
#pragma unroll
      for (int i = 0; i < 4; ++i)
        out[(size_t)(rbase + i) * kD + col] = acc[mt][nt][i];
    }
}

// ---------------------------------------------------------------------------
extern "C" void kernel_launch(void* const* d_in, const int* in_sizes, int n_in,
                              void* d_out, int out_size, void* d_ws, size_t ws_size,
                              hipStream_t stream) {
  const float* x     = (const float*)d_in[0];
  const float* fqk_w = (const float*)d_in[1];
  const float* fv_w  = (const float*)d_in[2];
  const float* wq    = (const float*)d_in[3];
  const float* wk    = (const float*)d_in[4];
  const float* wv    = (const float*)d_in[5];
  const float* f_neu = (const float*)d_in[6];
  const float* r_neu = (const float*)d_in[7];
  const float* WO    = (const float*)d_in[8];
  float* out = (float*)d_out;

  // ws layout (84 MB used, lifetime-overlapped):
  //  [0,8)   FT (dead after g_gemm)
  //  [8,16)  RT (dead after qkv_gemm)
  //  [16,80) G  (dead after reduce_h) -> Qb [16,32), Kb [32,48), VTg [48,64),
  //                                      AOb [64,80)
  //  [80,84) h_qk, h_v
  char* ws = (char*)d_ws;
  u16*   FT   = (u16*)  (ws);
  u16*   RT   = (u16*)  (ws + ((size_t)8u  << 20));
  u16*   G    = (u16*)  (ws + ((size_t)16u << 20));
  float* h_qk = (float*)(ws + ((size_t)80u << 20));
  float* h_v  = (float*)(ws + ((size_t)82u << 20));
  u16*   Qb   = (u16*)  (ws + ((size_t)16u << 20));
  u16*   Kb   = (u16*)  (ws + ((size_t)32u << 20));
  u16*   VTg  = (u16*)  (ws + ((size_t)48u << 20));
  u16*   AOb  = (u16*)  (ws + ((size_t)64u << 20));

  hipLaunchKernelGGL(t1_kernel, dim3(8, 64), dim3(256), 0, stream, f_neu, FT);
  hipLaunchKernelGGL(t2_kernel, dim3(8, 64), dim3(256), 0, stream, r_neu, RT);
  hipLaunchKernelGGL(g_gemm, dim3(32, 64), dim3(256), 0, stream, x, FT, G);
  hipLaunchKernelGGL(reduce_h, dim3(512), dim3(256), 0, stream,
                     G, fqk_w, fv_w, h_qk, h_v);
  hipLaunchKernelGGL(qkv_gemm, dim3(8, 64, 3), dim3(256), 0, stream,
                     h_qk, h_v, wq, wk, wv, RT, Qb, Kb, VTg);
  hipLaunchKernelGGL(attn_mfma, dim3(16, 16, 4), dim3(512), 0, stream,
                     Qb, Kb, VTg, AOb);
  hipLaunchKernelGGL(wo_gemm, dim3(8, 64), dim3(256), 0, stream,
                     AOb, WO, out);
}

// Round 6
// 544.970 us; speedup vs baseline: 8.0436x; 1.1636x over previous
//
#include <hip/hip_runtime.h>
#include <hip/hip_bf16.h>

// AttentionCircuit round 6:
//  - attn: transposed-score formulation (S^T = K Q^T, O^T = V^T P^T) -> per-lane
//    softmax state, 2 shuffles per reduction (was 16), packed bf16 stores;
//    16B staging loads; reversed qb for load balance; masked-wave skip.
//  - qkv: h-fragments hoisted to registers, Bs aliased into hs -> 3 blocks/CU.

namespace {
constexpr int kS = 2048;
constexpr int kD = 1024;
}

typedef unsigned short u16;
typedef __attribute__((ext_vector_type(4))) float f32x4;
typedef __attribute__((ext_vector_type(8))) short s8v;   // 8 bf16 = 4 VGPRs

union FragU { s8v s; unsigned u[4]; };

__device__ __forceinline__ u16 f2bf_bits(float f) {
  union { float f; unsigned u; } cv; cv.f = f;
  unsigned u = cv.u;
  unsigned r = u + 0x7fffu + ((u >> 16) & 1u);   // RNE
  return (u16)(r >> 16);
}
__device__ __forceinline__ float bf2f(u16 b) {
  union { unsigned u; float f; } cv; cv.u = ((unsigned)b) << 16; return cv.f;
}
__device__ __forceinline__ unsigned pk_bf16(float a, float b) {
  __hip_bfloat162 h = __float22bfloat162_rn(make_float2(a, b));
  union { __hip_bfloat162 h; unsigned u; } cv; cv.h = h; return cv.u;
}

// ---------------------------------------------------------------------------
// T1: FT[n*64+r][d] = f[n][d][r]  (bf16)  — B^T layout for G-GEMM.
// ---------------------------------------------------------------------------
__global__ __launch_bounds__(256) void t1_kernel(const float* __restrict__ f,
                                                 u16* __restrict__ FT) {
  __shared__ float Tt[64 * 132];
  const int tid = threadIdx.x;
  const int d0 = blockIdx.x * 128;
  const int n  = blockIdx.y;
#pragma unroll
  for (int e = 0; e < 8; ++e) {
    int flat = tid + e * 256;            // 0..2047
    int dd = flat >> 4, r4 = (flat & 15) * 4;
    float4 v = *(const float4*)&f[((size_t)n * kD + d0 + dd) * 64 + r4];
    Tt[(r4 + 0) * 132 + dd] = v.x;
    Tt[(r4 + 1) * 132 + dd] = v.y;
    Tt[(r4 + 2) * 132 + dd] = v.z;
    Tt[(r4 + 3) * 132 + dd] = v.w;
  }
  __syncthreads();
#pragma unroll
  for (int e = 0; e < 4; ++e) {
    int flat = tid + e * 256;            // 0..1023
    int r = flat >> 4, dq = (flat & 15) * 8;
    const float* p = &Tt[r * 132 + dq];
    uint4 o = { pk_bf16(p[0], p[1]), pk_bf16(p[2], p[3]),
                pk_bf16(p[4], p[5]), pk_bf16(p[6], p[7]) };
    *(uint4*)&FT[((size_t)n * 64 + r) * kD + d0 + dq] = o;
  }
}

// ---------------------------------------------------------------------------
// T2: RT[d][n*64+r] = r_neurons[n][r][d] (bf16) — B^T layout for QKV GEMM.
// ---------------------------------------------------------------------------
__global__ __launch_bounds__(256) void t2_kernel(const float* __restrict__ rn,
                                                 u16* __restrict__ RT) {
  __shared__ float Tt[128 * 68];
  const int tid = threadIdx.x;
  const int d0 = blockIdx.x * 128;
  const int n  = blockIdx.y;             // 0..63
#pragma unroll
  for (int e = 0; e < 8; ++e) {
    int flat = tid + e * 256;            // 0..2047
    int r = flat >> 5, d4 = (flat & 31) * 4;
    float4 v = *(const float4*)&rn[((size_t)n * 64 + r) * kD + d0 + d4];
    Tt[(d4 + 0) * 68 + r] = v.x;
    Tt[(d4 + 1) * 68 + r] = v.y;
    Tt[(d4 + 2) * 68 + r] = v.z;
    Tt[(d4 + 3) * 68 + r] = v.w;
  }
  __syncthreads();
#pragma unroll
  for (int e = 0; e < 4; ++e) {
    int flat = tid + e * 256;            // 0..1023
    int dd = flat >> 3, rq = (flat & 7) * 8;
    const float* p = &Tt[dd * 68 + rq];
    uint4 o = { pk_bf16(p[0], p[1]), pk_bf16(p[2], p[3]),
                pk_bf16(p[4], p[5]), pk_bf16(p[6], p[7]) };
    *(uint4*)&RT[((size_t)(d0 + dd)) * 4096 + n * 64 + rq] = o;
  }
}

// ---------------------------------------------------------------------------
// G-GEMM: G[t][g] = sum_d bf16(x[t,d]) * FT[g][d].  128x128 tile, BK=64.
// ---------------------------------------------------------------------------
__global__ __launch_bounds__(256) void g_gemm(const float* __restrict__ x,
                                              const u16* __restrict__ FT,
                                              u16* __restrict__ G) {
  __shared__ short As[128 * 72];
  __shared__ short Bs[128 * 72];
  const int tid = threadIdx.x;
  const int lane = tid & 63, wid = tid >> 6;
  const int wm = wid & 1, wn = wid >> 1;
  const int quad = lane >> 4, l15 = lane & 15;
  const int cT = blockIdx.x * 128;
  const int tok0 = blockIdx.y * 128;

  f32x4 acc[4][4];
#pragma unroll
  for (int mt = 0; mt < 4; ++mt)
#pragma unroll
    for (int nt = 0; nt < 4; ++nt) acc[mt][nt] = {0.f, 0.f, 0.f, 0.f};

#pragma unroll 1
  for (int d0 = 0; d0 < kD; d0 += 64) {
    __syncthreads();
#pragma unroll
    for (int e = 0; e < 8; ++e) {                 // A: x fp32 -> bf16, 128x64
      int flat = tid + e * 256;                   // 0..2047 (float4 units)
      int row = flat >> 4, kq = (flat & 15) * 4;
      float4 v = *(const float4*)&x[(size_t)(tok0 + row) * kD + d0 + kq];
      uint2 o = { pk_bf16(v.x, v.y), pk_bf16(v.z, v.w) };
      *(uint2*)&As[row * 72 + kq] = o;
    }
#pragma unroll
    for (int e = 0; e < 4; ++e) {                 // B: FT bf16 direct, 128x64
      int flat = tid + e * 256;                   // 0..1023 (16B units, 8/row)
      int col = flat >> 3, kq = (flat & 7) * 8;
      *(s8v*)&Bs[col * 72 + kq] =
          *(const s8v*)&FT[(size_t)(cT + col) * kD + d0 + kq];
    }
    __syncthreads();
    s8v a0[4], a1[4], b0[4], b1[4];
#pragma unroll
    for (int mt = 0; mt < 4; ++mt) {
      const short* p = &As[(wm * 64 + mt * 16 + l15) * 72 + quad * 8];
      a0[mt] = *(const s8v*)p;
      a1[mt] = *(const s8v*)(p + 32);
    }
#pragma unroll
    for (int nt = 0; nt < 4; ++nt) {
      const short* p = &Bs[(wn * 64 + nt * 16 + l15) * 72 + quad * 8];
      b0[nt] = *(const s8v*)p;
      b1[nt] = *(const s8v*)(p + 32);
    }
#pragma unroll
    for (int mt = 0; mt < 4; ++mt)
#pragma unroll
      for (int nt = 0; nt < 4; ++nt) {
        acc[mt][nt] = __builtin_amdgcn_mfma_f32_16x16x32_bf16(
            a0[mt], b0[nt], acc[mt][nt], 0, 0, 0);
        acc[mt][nt] = __builtin_amdgcn_mfma_f32_16x16x32_bf16(
            a1[mt], b1[nt], acc[mt][nt], 0, 0, 0);
      }
  }
#pragma unroll
  for (int mt = 0; mt < 4; ++mt)
#pragma unroll
    for (int nt = 0; nt < 4; ++nt) {
      int col = cT + wn * 64 + nt * 16 + l15;
      int rbase = tok0 + wm * 64 + mt * 16 + quad * 4;
#pragma unroll
      for (int i = 0; i < 4; ++i)
        G[(size_t)(rbase + i) * 4096 + col] = f2bf_bits(acc[mt][nt][i]);
    }
}

// ---------------------------------------------------------------------------
// reduce_h: h_qk[t][r] = sum_n fqk_w[t][n]*G[t][n*64+r]; h_v from cols 2048+.
// ---------------------------------------------------------------------------
__global__ __launch_bounds__(256) void reduce_h(const u16* __restrict__ G,
                                                const float* __restrict__ fqk_w,
                                                const float* __restrict__ fv_w,
                                                float* __restrict__ h_qk,
                                                float* __restrict__ h_v) {
  int idx = blockIdx.x * 256 + threadIdx.x;    // 0..131071
  int t = idx >> 4, r4 = (idx & 15) * 4;
  float4 aq = {0.f, 0.f, 0.f, 0.f}, av = {0.f, 0.f, 0.f, 0.f};
  const u16* gq = &G[(size_t)t * 4096 + r4];
  const u16* gv = gq + 2048;
#pragma unroll 4
  for (int n = 0; n < 32; ++n) {
    float wa = fqk_w[t * 32 + n];
    float wb = fv_w[t * 32 + n];
    ushort4 g1 = *(const ushort4*)&gq[n * 64];
    ushort4 g2 = *(const ushort4*)&gv[n * 64];
    aq.x += wa * bf2f(g1.x); aq.y += wa * bf2f(g1.y);
    aq.z += wa * bf2f(g1.z); aq.w += wa * bf2f(g1.w);
    av.x += wb * bf2f(g2.x); av.y += wb * bf2f(g2.y);
    av.z += wb * bf2f(g2.z); av.w += wb * bf2f(g2.w);
  }
  *(float4*)&h_qk[t * 64 + r4] = aq;
  *(float4*)&h_v[t * 64 + r4] = av;
}

// ---------------------------------------------------------------------------
// QKV-GEMM: C[t][d] = sum_g (w[t,n]*h[t,r]) * RT[d][g0+g],  g=n*64+r, K=2048.
// h-fragments hoisted to registers; Bs aliases hs (hs dead after hoist).
// which: 0->Qb (bf16, [t][d]), 1->Kb (bf16, [t][d]), 2->VTg ([b][h][d][s]).
// ---------------------------------------------------------------------------
__global__ __launch_bounds__(256) void qkv_gemm(
    const float* __restrict__ h_qk, const float* __restrict__ h_v,
    const float* __restrict__ wq, const float* __restrict__ wk,
    const float* __restrict__ wv, const u16* __restrict__ RT,
    u16* __restrict__ Qb, u16* __restrict__ Kb, u16* __restrict__ VTg) {
  __shared__ float hs[128 * 68];                 // 34816 B; aliased by Bs below
  __shared__ float wsl[128 * 33];
  short* Bs = (short*)hs;                        // needs 128*72*2 = 18432 B
  const int tid = threadIdx.x;
  const int lane = tid & 63, wid = tid >> 6;
  const int wm = wid & 1, wn = wid >> 1;
  const int quad = lane >> 4, l15 = lane & 15;
  const int dT = blockIdx.x * 128;
  const int tok0 = blockIdx.y * 128;
  const int which = blockIdx.z;
  const float* __restrict__ h = (which == 2) ? h_v : h_qk;
  const float* __restrict__ w = (which == 0) ? wq : (which == 1) ? wk : wv;
  const int g0 = (which == 2) ? 2048 : 0;

#pragma unroll
  for (int e = 0; e < 8; ++e) {                  // h tile: 128x64 fp32
    int flat = tid + e * 256;                    // 0..2047 (float4 units)
    int row = flat >> 4, rq = (flat & 15) * 4;
    *(float4*)&hs[row * 68 + rq] =
        *(const float4*)&h[(size_t)(tok0 + row) * 64 + rq];
  }
#pragma unroll
  for (int e = 0; e < 16; ++e) {                 // w tile: 128x32 fp32
    int flat = tid + e * 256;                    // 0..4095
    int row = flat >> 5, nn = flat & 31;
    wsl[row * 33 + nn] = w[(size_t)(tok0 + row) * 32 + nn];
  }
  __syncthreads();

  // hoist h fragments: per mt, this lane's row needs h[quad*8..+7] and +32
  f32x4 hreg[4][4];
#pragma unroll
  for (int mt = 0; mt < 4; ++mt) {
    const float* hp = &hs[(wm * 64 + mt * 16 + l15) * 68 + quad * 8];
    hreg[mt][0] = *(const f32x4*)hp;
    hreg[mt][1] = *(const f32x4*)(hp + 4);
    hreg[mt][2] = *(const f32x4*)(hp + 32);
    hreg[mt][3] = *(const f32x4*)(hp + 36);
  }

  f32x4 acc[4][4];
#pragma unroll
  for (int mt = 0; mt < 4; ++mt)
#pragma unroll
    for (int nt = 0; nt < 4; ++nt) acc[mt][nt] = {0.f, 0.f, 0.f, 0.f};

#pragma unroll 1
  for (int n = 0; n < 32; ++n) {
    __syncthreads();                             // hs reads done (n=0) / prev iter
#pragma unroll
    for (int e = 0; e < 4; ++e) {                // B: 128 cols x 64 k
      int flat = tid + e * 256;                  // 0..1023 (16B units, 8/row)
      int col = flat >> 3, kq = (flat & 7) * 8;
      *(s8v*)&Bs[col * 72 + kq] =
          *(const s8v*)&RT[(size_t)(dT + col) * 4096 + g0 + n * 64 + kq];
    }
    __syncthreads();
    s8v a0[4], a1[4], b0[4], b1[4];
#pragma unroll
    for (int mt = 0; mt < 4; ++mt) {
      float wv_ = wsl[(wm * 64 + mt * 16 + l15) * 33 + n];
      FragU fa, fb;
      fa.u[0] = pk_bf16(wv_ * hreg[mt][0][0], wv_ * hreg[mt][0][1]);
      fa.u[1] = pk_bf16(wv_ * hreg[mt][0][2], wv_ * hreg[mt][0][3]);
      fa.u[2] = pk_bf16(wv_ * hreg[mt][1][0], wv_ * hreg[mt][1][1]);
      fa.u[3] = pk_bf16(wv_ * hreg[mt][1][2], wv_ * hreg[mt][1][3]);
      a0[mt] = fa.s;
      fb.u[0] = pk_bf16(wv_ * hreg[mt][2][0], wv_ * hreg[mt][2][1]);
      fb.u[1] = pk_bf16(wv_ * hreg[mt][2][2], wv_ * hreg[mt][2][3]);
      fb.u[2] = pk_bf16(wv_ * hreg[mt][3][0], wv_ * hreg[mt][3][1]);
      fb.u[3] = pk_bf16(wv_ * hreg[mt][3][2], wv_ * hreg[mt][3][3]);
      a1[mt] = fb.s;
    }
#pragma unroll
    for (int nt = 0; nt < 4; ++nt) {
      const short* p = &Bs[(wn * 64 + nt * 16 + l15) * 72 + quad * 8];
      b0[nt] = *(const s8v*)p;
      b1[nt] = *(const s8v*)(p + 32);
    }
#pragma unroll
    for (int mt = 0; mt < 4; ++mt)
#pragma unroll
      for (int nt = 0; nt < 4; ++nt) {
        acc[mt][nt] = __builtin_amdgcn_mfma_f32_16x16x32_bf16(
            a0[mt], b0[nt], acc[mt][nt], 0, 0, 0);
        acc[mt][nt] = __builtin_amdgcn_mfma_f32_16x16x32_bf16(
            a1[mt], b1[nt], acc[mt][nt], 0, 0, 0);
      }
  }

  if (which < 2) {
    u16* __restrict__ O = (which == 0) ? Qb : Kb;
#pragma unroll
    for (int mt = 0; mt < 4; ++mt)
#pragma unroll
      for (int nt = 0; nt < 4; ++nt) {
        int col = dT + wn * 64 + nt * 16 + l15;
        int rbase = tok0 + wm * 64 + mt * 16 + quad * 4;
#pragma unroll
        for (int i = 0; i < 4; ++i)
          O[(size_t)(rbase + i) * kD + col] = f2bf_bits(acc[mt][nt][i]);
      }
  } else {
#pragma unroll
    for (int mt = 0; mt < 4; ++mt)
#pragma unroll
      for (int nt = 0; nt < 4; ++nt) {
        int d = dT + wn * 64 + nt * 16 + l15;
        int hh = d >> 6, dl = d & 63;
        int t = tok0 + wm * 64 + mt * 16 + quad * 4;   // 4 consecutive tokens
        int bb = t >> 11, sl = t & 2047;
        ushort4 u = { f2bf_bits(acc[mt][nt][0]), f2bf_bits(acc[mt][nt][1]),
                      f2bf_bits(acc[mt][nt][2]), f2bf_bits(acc[mt][nt][3]) };
        *(ushort4*)&VTg[(((size_t)bb * 16 + hh) * 64 + dl) * kS + sl] = u;
      }
  }
}

// ---------------------------------------------------------------------------
// Flash attention, transposed-score MFMA. Block = (qb, head, batch): 128
// q-rows, 8 waves, wave w owns q rows w*16..w*16+15 (q = column index of all
// MFMA outputs -> per-lane softmax state, 2-shuffle reductions).
// ---------------------------------------------------------------------------
__global__ __launch_bounds__(512) void attn_mfma(
    const u16* __restrict__ Qb, const u16* __restrict__ Kb,
    const u16* __restrict__ VTg, u16* __restrict__ AOb)
{
  __shared__ short Qs[128 * 72];      // [q-row][d]
  __shared__ short Ks[64 * 72];       // [k-tok][d]
  __shared__ short VTs[64 * 72];      // [d][k-tok]
  __shared__ short Ps[8][16 * 72];    // per-wave P strip [q-local][k-tok]
  const int tid = threadIdx.x;
  const int lane = tid & 63, w = tid >> 6;       // w 0..7
  const int quad = lane >> 4, l15 = lane & 15;
  const int qb = 15 - blockIdx.x;                // reversed: longest first
  const int hh = blockIdx.y, b = blockIdx.z;
  const int dh = hh * 64;
  const size_t qrow0 = (size_t)b * kS + (size_t)qb * 128;
  const int ktmax = qb * 2 + 1;
  const u16* __restrict__ vbase = VTg + ((size_t)(b * 16 + hh) * 64) * kS;

  const int prow = tid >> 3;                     // 0..63
  const int pd8  = (tid & 7) * 8;                // 16B staging mapping

  // stage Q (128x64) + K/V tile 0, 16B loads
  *(uint4*)&Qs[prow * 72 + pd8] =
      *(const uint4*)&Qb[(qrow0 + prow) * kD + dh + pd8];
  *(uint4*)&Qs[(prow + 64) * 72 + pd8] =
      *(const uint4*)&Qb[(qrow0 + prow + 64) * kD + dh + pd8];
  *(uint4*)&Ks[prow * 72 + pd8] =
      *(const uint4*)&Kb[((size_t)b * kS + prow) * kD + dh + pd8];
  *(uint4*)&VTs[prow * 72 + pd8] =
      *(const uint4*)&vbase[(size_t)prow * kS + pd8];
  __syncthreads();

  // loop-invariant Q fragments (B-operand: n = q = l15, k = d)
  s8v bq0 = *(const s8v*)&Qs[(w * 16 + l15) * 72 + quad * 8];
  s8v bq1 = *(const s8v*)&Qs[(w * 16 + l15) * 72 + 32 + quad * 8];

  const int q_g = qb * 128 + w * 16 + l15;       // this lane's global q row
  const int qmax_w = qb * 128 + w * 16 + 15;
  float m = -INFINITY, l = 0.f;
  f32x4 O[4];                                    // O^T: row d = dt*16+quad*4+i, col q
#pragma unroll
  for (int dt = 0; dt < 4; ++dt) O[dt] = {0.f, 0.f, 0.f, 0.f};

#pragma unroll 1
  for (int kt = 0; kt <= ktmax; ++kt) {
    // prefetch next K/V tile (16B/lane)
    uint4 pk, pv;
    if (kt < ktmax) {
      const size_t krn = (size_t)b * kS + (size_t)(kt + 1) * 64;
      pk = *(const uint4*)&Kb[(krn + prow) * kD + dh + pd8];
      pv = *(const uint4*)&vbase[(size_t)prow * kS + (kt + 1) * 64 + pd8];
    }

    if (kt * 64 <= qmax_w) {                     // wave has unmasked work
      // ---- S^T = K Q^T: rows = k-tok, cols = q ----
      f32x4 st[4];
#pragma unroll
      for (int nt = 0; nt < 4; ++nt) {
        const short* p = &Ks[(nt * 16 + l15) * 72 + quad * 8];
        s8v ak0 = *(const s8v*)p;
        s8v ak1 = *(const s8v*)(p + 32);
        f32x4 z = {0.f, 0.f, 0.f, 0.f};
        z = __builtin_amdgcn_mfma_f32_16x16x32_bf16(ak0, bq0, z, 0, 0, 0);
        st[nt] = __builtin_amdgcn_mfma_f32_16x16x32_bf16(ak1, bq1, z, 0, 0, 0);
      }

      if (kt * 64 + 63 > qb * 128 + w * 16) {    // causal mask on this tile
#pragma unroll
        for (int nt = 0; nt < 4; ++nt)
#pragma unroll
          for (int i = 0; i < 4; ++i)
            if (kt * 64 + nt * 16 + quad * 4 + i > q_g) st[nt][i] = -1e30f;
      }

      // ---- per-lane online softmax over 16 regs + 2 shuffles ----
      float pm = -INFINITY;
#pragma unroll
      for (int nt = 0; nt < 4; ++nt)
#pragma unroll
        for (int i = 0; i < 4; ++i) pm = fmaxf(pm, st[nt][i]);
      pm = fmaxf(pm, __shfl_xor(pm, 16, 64));
      pm = fmaxf(pm, __shfl_xor(pm, 32, 64));
      float mn = fmaxf(m, pm);
      float alpha = __expf((m - mn) * 0.125f);
      m = mn;
      float p[4][4];
      float r = 0.f;
#pragma unroll
      for (int nt = 0; nt < 4; ++nt)
#pragma unroll
        for (int i = 0; i < 4; ++i) {
          p[nt][i] = __expf((st[nt][i] - mn) * 0.125f);
          r += p[nt][i];
        }
      r += __shfl_xor(r, 16, 64);
      r += __shfl_xor(r, 32, 64);
      l = l * alpha + r;
#pragma unroll
      for (int dt = 0; dt < 4; ++dt)
#pragma unroll
        for (int i = 0; i < 4; ++i) O[dt][i] *= alpha;

      // ---- P strip (packed 8B stores), then O^T += V^T P^T ----
#pragma unroll
      for (int nt = 0; nt < 4; ++nt) {
        uint2 o = { pk_bf16(p[nt][0], p[nt][1]), pk_bf16(p[nt][2], p[nt][3]) };
        *(uint2*)&Ps[w][l15 * 72 + nt * 16 + quad * 4] = o;
      }
      s8v bp0 = *(const s8v*)&Ps[w][l15 * 72 + quad * 8];
      s8v bp1 = *(const s8v*)&Ps[w][l15 * 72 + 32 + quad * 8];
#pragma unroll
      for (int dt = 0; dt < 4; ++dt) {
        const short* p2 = &VTs[(dt * 16 + l15) * 72 + quad * 8];
        s8v av0 = *(const s8v*)p2;
        s8v av1 = *(const s8v*)(p2 + 32);
        O[dt] = __builtin_amdgcn_mfma_f32_16x16x32_bf16(av0, bp0, O[dt], 0, 0, 0);
        O[dt] = __builtin_amdgcn_mfma_f32_16x16x32_bf16(av1, bp1, O[dt], 0, 0, 0);
      }
    }

    __syncthreads();                             // all reads of Ks/VTs done
    if (kt < ktmax) {
      *(uint4*)&Ks[prow * 72 + pd8] = pk;
      *(uint4*)&VTs[prow * 72 + pd8] = pv;
    }
    __syncthreads();
  }

  // epilogue: O^T -> AOb[q][d], packed 8B stores
  const float inv = 1.f / l;
  const size_t row = qrow0 + w * 16 + l15;
#pragma unroll
  for (int dt = 0; dt < 4; ++dt) {
    uint2 o = { pk_bf16(O[dt][0] * inv, O[dt][1] * inv),
                pk_bf16(O[dt][2] * inv, O[dt][3] * inv) };
    *(uint2*)&AOb[row * kD + dh + dt * 16 + quad * 4] = o;
  }
}

// ---------------------------------------------------------------------------
// WO-GEMM: out[t][d] = sum_e AO[t][e] * W_O[d][e].  BK=64.
// ---------------------------------------------------------------------------
__global__ __launch_bounds__(256) void wo_gemm(const u16* __restrict__ AOb,
                                               const float* __restrict__ WO,
                                               float* __restrict__ out) {
  __shared__ short As[128 * 72];
  __shared__ short Bs[128 * 72];
  const int tid = threadIdx.x;
  const int lane = tid & 63, wid = tid >> 6;
  const int wm = wid & 1, wn = wid >> 1;
  const int quad = lane >> 4, l15 = lane & 15;
  const int dT = blockIdx.x * 128;
  const int tok0 = blockIdx.y * 128;

  f32x4 acc[4][4];
#pragma unroll
  for (int mt = 0; mt < 4; ++mt)
#pragma unroll
    for (int nt = 0; nt < 4; ++nt) acc[mt][nt] = {0.f, 0.f, 0.f, 0.f};

#pragma unroll 1
  for (int e0 = 0; e0 < kD; e0 += 64) {
    __syncthreads();
#pragma unroll
    for (int e = 0; e < 4; ++e) {                 // A: AO bf16 direct, 128x64
      int flat = tid + e * 256;                   // 0..1023 (16B units, 8/row)
      int row = flat >> 3, kq = (flat & 7) * 8;
      *(s8v*)&As[row * 72 + kq] =
          *(const s8v*)&AOb[(size_t)(tok0 + row) * kD + e0 + kq];
    }
#pragma unroll
    for (int e = 0; e < 8; ++e) {                 // B: W_O fp32 -> bf16
      int flat = tid + e * 256;                   // 0..2047 (float4 units)
      int col = flat >> 4, kq = (flat & 15) * 4;
      float4 v = *(const float4*)&WO[(size_t)(dT + col) * kD + e0 + kq];
      uint2 o = { pk_bf16(v.x, v.y), pk_bf16(v.z, v.w) };
      *(uint2*)&Bs[col * 72 + kq] = o;
    }
    __syncthreads();
    s8v a0[4], a1[4], b0[4], b1[4];
#pragma unroll
    for (int mt = 0; mt < 4; ++mt) {
      const short* p = &As[(wm * 64 + mt * 16 + l15) * 72 + quad * 8];
      a0[mt] = *(const s8v*)p;
      a1[mt] = *(const s8v*)(p + 32);
    }
#pragma unroll
    for (int nt = 0; nt < 4; ++nt) {
      const short* p = &Bs[(wn * 64 + nt * 16 + l15) * 72 + quad * 8];
      b0[nt] = *(const s8v*)p;
      b1[nt] = *(const s8v*)(p + 32);
    }
#pragma unroll
    for (int mt = 0; mt < 4; ++mt)
#pragma unroll
      for (int nt = 0; nt < 4; ++nt) {
        acc[mt][nt] = __builtin_amdgcn_mfma_f32_16x16x32_bf16(
            a0[mt], b0[nt], acc[mt][nt], 0, 0, 0);
        acc[mt][nt] = __builtin_amdgcn_mfma_f32_16x16x32_bf16(
            a1[mt], b1[nt], acc[mt][nt], 0, 0, 0);
      }
  }
#pragma unroll
  for (int mt = 0; mt < 4; ++mt)
#pragma unroll
    for (int nt = 0; nt < 4; ++nt) {
      int col = dT + wn * 64 + nt * 16 + l15;
      int rbase = tok0 + wm * 64 + mt * 16 + quad * 4;
#pragma unroll
      for (int i = 0; i < 4; ++i)
        out[(size_t)(rbase + i) * kD + col] = acc[mt][nt][i];
    }
}

// ---------------------------------------------------------------------------
extern "C" void kernel_launch(void* const* d_in, const int* in_sizes, int n_in,
                              void* d_out, int out_size, void* d_ws, size_t ws_size,
                              hipStream_t stream) {
  const float* x     = (const float*)d_in[0];
  const float* fqk_w = (const float*)d_in[1];
  const float* fv_w  = (const float*)d_in[2];
  const float* wq    = (const float*)d_in[3];
  const float* wk    = (const float*)d_in[4];
  const float* wv    = (const float*)d_in[5];
  const float* f_neu = (const float*)d_in[6];
  const float* r_neu = (const float*)d_in[7];
  const float* WO    = (const float*)d_in[8];
  float* out = (float*)d_out;

  // ws layout (84 MB used, lifetime-overlapped):
  //  [0,8)   FT (dead after g_gemm)
  //  [8,16)  RT (dead after qkv_gemm)
  //  [16,80) G  (dead after reduce_h) -> Qb [16,32), Kb [32,48), VTg [48,64),
  //                                      AOb [64,80)
  //  [80,84) h_qk, h_v
  char* ws = (char*)d_ws;
  u16*   FT   = (u16*)  (ws);
  u16*   RT   = (u16*)  (ws + ((size_t)8u  << 20));
  u16*   G    = (u16*)  (ws + ((size_t)16u << 20));
  float* h_qk = (float*)(ws + ((size_t)80u << 20));
  float* h_v  = (float*)(ws + ((size_t)82u << 20));
  u16*   Qb   = (u16*)  (ws + ((size_t)16u << 20));
  u16*   Kb   = (u16*)  (ws + ((size_t)32u << 20));
  u16*   VTg  = (u16*)  (ws + ((size_t)48u << 20));
  u16*   AOb  = (u16*)  (ws + ((size_t)64u << 20));

  hipLaunchKernelGGL(t1_kernel, dim3(8, 64), dim3(256), 0, stream, f_neu, FT);
  hipLaunchKernelGGL(t2_kernel, dim3(8, 64), dim3(256), 0, stream, r_neu, RT);
  hipLaunchKernelGGL(g_gemm, dim3(32, 64), dim3(256), 0, stream, x, FT, G);
  hipLaunchKernelGGL(reduce_h, dim3(512), dim3(256), 0, stream,
                     G, fqk_w, fv_w, h_qk, h_v);
  hipLaunchKernelGGL(qkv_gemm, dim3(8, 64, 3), dim3(256), 0, stream,
                     h_qk, h_v, wq, wk, wv, RT, Qb, Kb, VTg);
  hipLaunchKernelGGL(attn_mfma, dim3(16, 16, 4), dim3(512), 0, stream,
                     Qb, Kb, VTg, AOb);
  hipLaunchKernelGGL(wo_gemm, dim3(8, 64), dim3(256), 0, stream,
                     AOb, WO, out);
}

// Round 8
// 493.582 us; speedup vs baseline: 8.8811x; 1.1041x over previous
//
#include <hip/hip_runtime.h>
#include <hip/hip_bf16.h>

// AttentionCircuit round 8 (= round 7 with gl_lds16 signature fixed to void*):
//  - x and W_O pre-converted to bf16 once (conv_x / conv_wo).
//  - g_gemm/qkv(B)/wo staged via __builtin_amdgcn_global_load_lds width=16
//    into UNPADDED LDS tiles with XOR swizzle (unit u of row r stored at
//    u^(r&7)) -> conflict-free ds_read_b128 fragments + no VGPR round-trip.
//  - attn unchanged from round 6.

namespace {
constexpr int kS = 2048;
constexpr int kD = 1024;
}

typedef unsigned short u16;
typedef __attribute__((ext_vector_type(4))) float f32x4;
typedef __attribute__((ext_vector_type(8))) short s8v;   // 8 bf16 = 4 VGPRs

union FragU { s8v s; unsigned u[4]; };

__device__ __forceinline__ u16 f2bf_bits(float f) {
  union { float f; unsigned u; } cv; cv.f = f;
  unsigned u = cv.u;
  unsigned r = u + 0x7fffu + ((u >> 16) & 1u);   // RNE
  return (u16)(r >> 16);
}
__device__ __forceinline__ float bf2f(u16 b) {
  union { unsigned u; float f; } cv; cv.u = ((unsigned)b) << 16; return cv.f;
}
__device__ __forceinline__ unsigned pk_bf16(float a, float b) {
  __hip_bfloat162 h = __float22bfloat162_rn(make_float2(a, b));
  union { __hip_bfloat162 h; unsigned u; } cv; cv.h = h; return cv.u;
}
// async global->LDS, 16B per lane; LDS dest = wave-uniform base + lane*16
__device__ __forceinline__ void gl_lds16(const void* g, void* l) {
  __builtin_amdgcn_global_load_lds(
      (const __attribute__((address_space(1))) unsigned int*)g,
      (__attribute__((address_space(3))) unsigned int*)l, 16, 0, 0);
}

// ---------------------------------------------------------------------------
// conv_x: x fp32 -> xb bf16 (8 elems/thread).  conv_wo: same for W_O.
// ---------------------------------------------------------------------------
__global__ __launch_bounds__(256) void conv_x(const float* __restrict__ x,
                                              u16* __restrict__ xb) {
  int idx = blockIdx.x * 256 + threadIdx.x;
  float4 v0 = ((const float4*)x)[idx * 2];
  float4 v1 = ((const float4*)x)[idx * 2 + 1];
  uint4 o = { pk_bf16(v0.x, v0.y), pk_bf16(v0.z, v0.w),
              pk_bf16(v1.x, v1.y), pk_bf16(v1.z, v1.w) };
  ((uint4*)xb)[idx] = o;
}

// ---------------------------------------------------------------------------
// T1: FT[n*64+r][d] = f[n][d][r]  (bf16)  — B^T layout for G-GEMM.
// ---------------------------------------------------------------------------
__global__ __launch_bounds__(256) void t1_kernel(const float* __restrict__ f,
                                                 u16* __restrict__ FT) {
  __shared__ float Tt[64 * 132];
  const int tid = threadIdx.x;
  const int d0 = blockIdx.x * 128;
  const int n  = blockIdx.y;
#pragma unroll
  for (int e = 0; e < 8; ++e) {
    int flat = tid + e * 256;            // 0..2047
    int dd = flat >> 4, r4 = (flat & 15) * 4;
    float4 v = *(const float4*)&f[((size_t)n * kD + d0 + dd) * 64 + r4];
    Tt[(r4 + 0) * 132 + dd] = v.x;
    Tt[(r4 + 1) * 132 + dd] = v.y;
    Tt[(r4 + 2) * 132 + dd] = v.z;
    Tt[(r4 + 3) * 132 + dd] = v.w;
  }
  __syncthreads();
#pragma unroll
  for (int e = 0; e < 4; ++e) {
    int flat = tid + e * 256;            // 0..1023
    int r = flat >> 4, dq = (flat & 15) * 8;
    const float* p = &Tt[r * 132 + dq];
    uint4 o = { pk_bf16(p[0], p[1]), pk_bf16(p[2], p[3]),
                pk_bf16(p[4], p[5]), pk_bf16(p[6], p[7]) };
    *(uint4*)&FT[((size_t)n * 64 + r) * kD + d0 + dq] = o;
  }
}

// ---------------------------------------------------------------------------
// T2: RT[d][n*64+r] = r_neurons[n][r][d] (bf16) — B^T layout for QKV GEMM.
// ---------------------------------------------------------------------------
__global__ __launch_bounds__(256) void t2_kernel(const float* __restrict__ rn,
                                                 u16* __restrict__ RT) {
  __shared__ float Tt[128 * 68];
  const int tid = threadIdx.x;
  const int d0 = blockIdx.x * 128;
  const int n  = blockIdx.y;             // 0..63
#pragma unroll
  for (int e = 0; e < 8; ++e) {
    int flat = tid + e * 256;            // 0..2047
    int r = flat >> 5, d4 = (flat & 31) * 4;
    float4 v = *(const float4*)&rn[((size_t)n * 64 + r) * kD + d0 + d4];
    Tt[(d4 + 0) * 68 + r] = v.x;
    Tt[(d4 + 1) * 68 + r] = v.y;
    Tt[(d4 + 2) * 68 + r] = v.z;
    Tt[(d4 + 3) * 68 + r] = v.w;
  }
  __syncthreads();
#pragma unroll
  for (int e = 0; e < 4; ++e) {
    int flat = tid + e * 256;            // 0..1023
    int dd = flat >> 3, rq = (flat & 7) * 8;
    const float* p = &Tt[dd * 68 + rq];
    uint4 o = { pk_bf16(p[0], p[1]), pk_bf16(p[2], p[3]),
                pk_bf16(p[4], p[5]), pk_bf16(p[6], p[7]) };
    *(uint4*)&RT[((size_t)(d0 + dd)) * 4096 + n * 64 + rq] = o;
  }
}

// ---------------------------------------------------------------------------
// G-GEMM: G[t][g] = sum_d xb[t,d] * FT[g][d].  128x128 tile, BK=64.
// Unpadded swizzled LDS (row r unit u at u^(r&7)), global_load_lds staging.
// ---------------------------------------------------------------------------
__global__ __launch_bounds__(256) void g_gemm(const u16* __restrict__ xb,
                                              const u16* __restrict__ FT,
                                              u16* __restrict__ G) {
  __shared__ short As[128 * 64];
  __shared__ short Bs[128 * 64];
  const int tid = threadIdx.x;
  const int lane = tid & 63, wid = tid >> 6;
  const int wm = wid & 1, wn = wid >> 1;
  const int quad = lane >> 4, l15 = lane & 15;
  const int cT = blockIdx.x * 128;
  const int tok0 = blockIdx.y * 128;

  f32x4 acc[4][4];
#pragma unroll
  for (int mt = 0; mt < 4; ++mt)
#pragma unroll
    for (int nt = 0; nt < 4; ++nt) acc[mt][nt] = {0.f, 0.f, 0.f, 0.f};

#pragma unroll 1
  for (int d0 = 0; d0 < kD; d0 += 64) {
    __syncthreads();
#pragma unroll
    for (int e = 0; e < 4; ++e) {                 // A: 128x64, DMA swizzled
      int flat = tid + e * 256;                   // 0..1023 (16B units)
      int r = flat >> 3, u = (flat & 7) ^ (r & 7);
      gl_lds16(&xb[(size_t)(tok0 + r) * kD + d0 + u * 8], &As[flat * 8]);
    }
#pragma unroll
    for (int e = 0; e < 4; ++e) {                 // B: 128x64, DMA swizzled
      int flat = tid + e * 256;
      int r = flat >> 3, u = (flat & 7) ^ (r & 7);
      gl_lds16(&FT[(size_t)(cT + r) * kD + d0 + u * 8], &Bs[flat * 8]);
    }
    __syncthreads();
    s8v a0[4], a1[4], b0[4], b1[4];
#pragma unroll
    for (int mt = 0; mt < 4; ++mt) {
      int r = wm * 64 + mt * 16 + l15;
      a0[mt] = *(const s8v*)&As[r * 64 + ((quad) ^ (r & 7)) * 8];
      a1[mt] = *(const s8v*)&As[r * 64 + ((4 + quad) ^ (r & 7)) * 8];
    }
#pragma unroll
    for (int nt = 0; nt < 4; ++nt) {
      int r = wn * 64 + nt * 16 + l15;
      b0[nt] = *(const s8v*)&Bs[r * 64 + ((quad) ^ (r & 7)) * 8];
      b1[nt] = *(const s8v*)&Bs[r * 64 + ((4 + quad) ^ (r & 7)) * 8];
    }
#pragma unroll
    for (int mt = 0; mt < 4; ++mt)
#pragma unroll
      for (int nt = 0; nt < 4; ++nt) {
        acc[mt][nt] = __builtin_amdgcn_mfma_f32_16x16x32_bf16(
            a0[mt], b0[nt], acc[mt][nt], 0, 0, 0);
        acc[mt][nt] = __builtin_amdgcn_mfma_f32_16x16x32_bf16(
            a1[mt], b1[nt], acc[mt][nt], 0, 0, 0);
      }
  }
#pragma unroll
  for (int mt = 0; mt < 4; ++mt)
#pragma unroll
    for (int nt = 0; nt < 4; ++nt) {
      int col = cT + wn * 64 + nt * 16 + l15;
      int rbase = tok0 + wm * 64 + mt * 16 + quad * 4;
#pragma unroll
      for (int i = 0; i < 4; ++i)
        G[(size_t)(rbase + i) * 4096 + col] = f2bf_bits(acc[mt][nt][i]);
    }
}

// ---------------------------------------------------------------------------
// reduce_h: h_qk[t][r] = sum_n fqk_w[t][n]*G[t][n*64+r]; h_v from cols 2048+.
// ---------------------------------------------------------------------------
__global__ __launch_bounds__(256) void reduce_h(const u16* __restrict__ G,
                                                const float* __restrict__ fqk_w,
                                                const float* __restrict__ fv_w,
                                                float* __restrict__ h_qk,
                                                float* __restrict__ h_v) {
  int idx = blockIdx.x * 256 + threadIdx.x;    // 0..131071
  int t = idx >> 4, r4 = (idx & 15) * 4;
  float4 aq = {0.f, 0.f, 0.f, 0.f}, av = {0.f, 0.f, 0.f, 0.f};
  const u16* gq = &G[(size_t)t * 4096 + r4];
  const u16* gv = gq + 2048;
#pragma unroll 4
  for (int n = 0; n < 32; ++n) {
    float wa = fqk_w[t * 32 + n];
    float wb = fv_w[t * 32 + n];
    ushort4 g1 = *(const ushort4*)&gq[n * 64];
    ushort4 g2 = *(const ushort4*)&gv[n * 64];
    aq.x += wa * bf2f(g1.x); aq.y += wa * bf2f(g1.y);
    aq.z += wa * bf2f(g1.z); aq.w += wa * bf2f(g1.w);
    av.x += wb * bf2f(g2.x); av.y += wb * bf2f(g2.y);
    av.z += wb * bf2f(g2.z); av.w += wb * bf2f(g2.w);
  }
  *(float4*)&h_qk[t * 64 + r4] = aq;
  *(float4*)&h_v[t * 64 + r4] = av;
}

// ---------------------------------------------------------------------------
// QKV-GEMM: C[t][d] = sum_g (w[t,n]*h[t,r]) * RT[d][g0+g],  g=n*64+r, K=2048.
// B staged via global_load_lds swizzled; h fragments hoisted to registers.
// which: 0->Qb (bf16, [t][d]), 1->Kb (bf16, [t][d]), 2->VTg ([b][h][d][s]).
// ---------------------------------------------------------------------------
__global__ __launch_bounds__(256) void qkv_gemm(
    const float* __restrict__ h_qk, const float* __restrict__ h_v,
    const float* __restrict__ wq, const float* __restrict__ wk,
    const float* __restrict__ wv, const u16* __restrict__ RT,
    u16* __restrict__ Qb, u16* __restrict__ Kb, u16* __restrict__ VTg) {
  __shared__ float hs[128 * 68];                 // aliased by Bs after hoist
  __shared__ float wsl[128 * 33];
  short* Bs = (short*)hs;                        // needs 128*64*2 = 16 KB
  const int tid = threadIdx.x;
  const int lane = tid & 63, wid = tid >> 6;
  const int wm = wid & 1, wn = wid >> 1;
  const int quad = lane >> 4, l15 = lane & 15;
  const int dT = blockIdx.x * 128;
  const int tok0 = blockIdx.y * 128;
  const int which = blockIdx.z;
  const float* __restrict__ h = (which == 2) ? h_v : h_qk;
  const float* __restrict__ w = (which == 0) ? wq : (which == 1) ? wk : wv;
  const int g0 = (which == 2) ? 2048 : 0;

#pragma unroll
  for (int e = 0; e < 8; ++e) {                  // h tile: 128x64 fp32
    int flat = tid + e * 256;                    // 0..2047 (float4 units)
    int row = flat >> 4, rq = (flat & 15) * 4;
    *(float4*)&hs[row * 68 + rq] =
        *(const float4*)&h[(size_t)(tok0 + row) * 64 + rq];
  }
#pragma unroll
  for (int e = 0; e < 16; ++e) {                 // w tile: 128x32 fp32
    int flat = tid + e * 256;                    // 0..4095
    int row = flat >> 5, nn = flat & 31;
    wsl[row * 33 + nn] = w[(size_t)(tok0 + row) * 32 + nn];
  }
  __syncthreads();

  f32x4 hreg[4][4];
#pragma unroll
  for (int mt = 0; mt < 4; ++mt) {
    const float* hp = &hs[(wm * 64 + mt * 16 + l15) * 68 + quad * 8];
    hreg[mt][0] = *(const f32x4*)hp;
    hreg[mt][1] = *(const f32x4*)(hp + 4);
    hreg[mt][2] = *(const f32x4*)(hp + 32);
    hreg[mt][3] = *(const f32x4*)(hp + 36);
  }

  f32x4 acc[4][4];
#pragma unroll
  for (int mt = 0; mt < 4; ++mt)
#pragma unroll
    for (int nt = 0; nt < 4; ++nt) acc[mt][nt] = {0.f, 0.f, 0.f, 0.f};

#pragma unroll 1
  for (int n = 0; n < 32; ++n) {
    __syncthreads();                             // hs reads done / prev iter
#pragma unroll
    for (int e = 0; e < 4; ++e) {                // B: 128x64, DMA swizzled
      int flat = tid + e * 256;                  // 0..1023 (16B units)
      int r = flat >> 3, u = (flat & 7) ^ (r & 7);
      gl_lds16(&RT[(size_t)(dT + r) * 4096 + g0 + n * 64 + u * 8],
               &Bs[flat * 8]);
    }
    __syncthreads();
    s8v a0[4], a1[4], b0[4], b1[4];
#pragma unroll
    for (int mt = 0; mt < 4; ++mt) {
      float wv_ = wsl[(wm * 64 + mt * 16 + l15) * 33 + n];
      FragU fa, fb;
      fa.u[0] = pk_bf16(wv_ * hreg[mt][0][0], wv_ * hreg[mt][0][1]);
      fa.u[1] = pk_bf16(wv_ * hreg[mt][0][2], wv_ * hreg[mt][0][3]);
      fa.u[2] = pk_bf16(wv_ * hreg[mt][1][0], wv_ * hreg[mt][1][1]);
      fa.u[3] = pk_bf16(wv_ * hreg[mt][1][2], wv_ * hreg[mt][1][3]);
      a0[mt] = fa.s;
      fb.u[0] = pk_bf16(wv_ * hreg[mt][2][0], wv_ * hreg[mt][2][1]);
      fb.u[1] = pk_bf16(wv_ * hreg[mt][2][2], wv_ * hreg[mt][2][3]);
      fb.u[2] = pk_bf16(wv_ * hreg[mt][3][0], wv_ * hreg[mt][3][1]);
      fb.u[3] = pk_bf16(wv_ * hreg[mt][3][2], wv_ * hreg[mt][3][3]);
      a1[mt] = fb.s;
    }
#pragma unroll
    for (int nt = 0; nt < 4; ++nt) {
      int r = wn * 64 + nt * 16 + l15;
      b0[nt] = *(const s8v*)&Bs[r * 64 + ((quad) ^ (r & 7)) * 8];
      b1[nt] = *(const s8v*)&Bs[r * 64 + ((4 + quad) ^ (r & 7)) * 8];
    }
#pragma unroll
    for (int mt = 0; mt < 4; ++mt)
#pragma unroll
      for (int nt = 0; nt < 4; ++nt) {
        acc[mt][nt] = __builtin_amdgcn_mfma_f32_16x16x32_bf16(
            a0[mt], b0[nt], acc[mt][nt], 0, 0, 0);
        acc[mt][nt] = __builtin_amdgcn_mfma_f32_16x16x32_bf16(
            a1[mt], b1[nt], acc[mt][nt], 0, 0, 0);
      }
  }

  if (which < 2) {
    u16* __restrict__ O = (which == 0) ? Qb : Kb;
#pragma unroll
    for (int mt = 0; mt < 4; ++mt)
#pragma unroll
      for (int nt = 0; nt < 4; ++nt) {
        int col = dT + wn * 64 + nt * 16 + l15;
        int rbase = tok0 + wm * 64 + mt * 16 + quad * 4;
#pragma unroll
        for (int i = 0; i < 4; ++i)
          O[(size_t)(rbase + i) * kD + col] = f2bf_bits(acc[mt][nt][i]);
      }
  } else {
#pragma unroll
    for (int mt = 0; mt < 4; ++mt)
#pragma unroll
      for (int nt = 0; nt < 4; ++nt) {
        int d = dT + wn * 64 + nt * 16 + l15;
        int hh = d >> 6, dl = d & 63;
        int t = tok0 + wm * 64 + mt * 16 + quad * 4;   // 4 consecutive tokens
        int bb = t >> 11, sl = t & 2047;
        ushort4 u = { f2bf_bits(acc[mt][nt][0]), f2bf_bits(acc[mt][nt][1]),
                      f2bf_bits(acc[mt][nt][2]), f2bf_bits(acc[mt][nt][3]) };
        *(ushort4*)&VTg[(((size_t)bb * 16 + hh) * 64 + dl) * kS + sl] = u;
      }
  }
}

// ---------------------------------------------------------------------------
// conv_wo: W_O fp32 -> bf16 (runs after qkv_gemm, into dead RT region).
// ---------------------------------------------------------------------------
__global__ __launch_bounds__(256) void conv_wo(const float* __restrict__ WO,
                                               u16* __restrict__ wob) {
  int idx = blockIdx.x * 256 + threadIdx.x;
  float4 v0 = ((const float4*)WO)[idx * 2];
  float4 v1 = ((const float4*)WO)[idx * 2 + 1];
  uint4 o = { pk_bf16(v0.x, v0.y), pk_bf16(v0.z, v0.w),
              pk_bf16(v1.x, v1.y), pk_bf16(v1.z, v1.w) };
  ((uint4*)wob)[idx] = o;
}

// ---------------------------------------------------------------------------
// Flash attention, transposed-score MFMA (unchanged from round 6).
// ---------------------------------------------------------------------------
__global__ __launch_bounds__(512) void attn_mfma(
    const u16* __restrict__ Qb, const u16* __restrict__ Kb,
    const u16* __restrict__ VTg, u16* __restrict__ AOb)
{
  __shared__ short Qs[128 * 72];      // [q-row][d]
  __shared__ short Ks[64 * 72];       // [k-tok][d]
  __shared__ short VTs[64 * 72];      // [d][k-tok]
  __shared__ short Ps[8][16 * 72];    // per-wave P strip [q-local][k-tok]
  const int tid = threadIdx.x;
  const int lane = tid & 63, w = tid >> 6;       // w 0..7
  const int quad = lane >> 4, l15 = lane & 15;
  const int qb = 15 - blockIdx.x;                // reversed: longest first
  const int hh = blockIdx.y, b = blockIdx.z;
  const int dh = hh * 64;
  const size_t qrow0 = (size_t)b * kS + (size_t)qb * 128;
  const int ktmax = qb * 2 + 1;
  const u16* __restrict__ vbase = VTg + ((size_t)(b * 16 + hh) * 64) * kS;

  const int prow = tid >> 3;                     // 0..63
  const int pd8  = (tid & 7) * 8;                // 16B staging mapping

  *(uint4*)&Qs[prow * 72 + pd8] =
      *(const uint4*)&Qb[(qrow0 + prow) * kD + dh + pd8];
  *(uint4*)&Qs[(prow + 64) * 72 + pd8] =
      *(const uint4*)&Qb[(qrow0 + prow + 64) * kD + dh + pd8];
  *(uint4*)&Ks[prow * 72 + pd8] =
      *(const uint4*)&Kb[((size_t)b * kS + prow) * kD + dh + pd8];
  *(uint4*)&VTs[prow * 72 + pd8] =
      *(const uint4*)&vbase[(size_t)prow * kS + pd8];
  __syncthreads();

  s8v bq0 = *(const s8v*)&Qs[(w * 16 + l15) * 72 + quad * 8];
  s8v bq1 = *(const s8v*)&Qs[(w * 16 + l15) * 72 + 32 + quad * 8];

  const int q_g = qb * 128 + w * 16 + l15;
  const int qmax_w = qb * 128 + w * 16 + 15;
  float m = -INFINITY, l = 0.f;
  f32x4 O[4];
#pragma unroll
  for (int dt = 0; dt < 4; ++dt) O[dt] = {0.f, 0.f, 0.f, 0.f};

#pragma unroll 1
  for (int kt = 0; kt <= ktmax; ++kt) {
    uint4 pk, pv;
    if (kt < ktmax) {
      const size_t krn = (size_t)b * kS + (size_t)(kt + 1) * 64;
      pk = *(const uint4*)&Kb[(krn + prow) * kD + dh + pd8];
      pv = *(const uint4*)&vbase[(size_t)prow * kS + (kt + 1) * 64 + pd8];
    }

    if (kt * 64 <= qmax_w) {
      f32x4 st[4];
#pragma unroll
      for (int nt = 0; nt < 4; ++nt) {
        const short* p = &Ks[(nt * 16 + l15) * 72 + quad * 8];
        s8v ak0 = *(const s8v*)p;
        s8v ak1 = *(const s8v*)(p + 32);
        f32x4 z = {0.f, 0.f, 0.f, 0.f};
        z = __builtin_amdgcn_mfma_f32_16x16x32_bf16(ak0, bq0, z, 0, 0, 0);
        st[nt] = __builtin_amdgcn_mfma_f32_16x16x32_bf16(ak1, bq1, z, 0, 0, 0);
      }

      if (kt * 64 + 63 > qb * 128 + w * 16) {
#pragma unroll
        for (int nt = 0; nt < 4; ++nt)
#pragma unroll
          for (int i = 0; i < 4; ++i)
            if (kt * 64 + nt * 16 + quad * 4 + i > q_g) st[nt][i] = -1e30f;
      }

      float pm = -INFINITY;
#pragma unroll
      for (int nt = 0; nt < 4; ++nt)
#pragma unroll
        for (int i = 0; i < 4; ++i) pm = fmaxf(pm, st[nt][i]);
      pm = fmaxf(pm, __shfl_xor(pm, 16, 64));
      pm = fmaxf(pm, __shfl_xor(pm, 32, 64));
      float mn = fmaxf(m, pm);
      float alpha = __expf((m - mn) * 0.125f);
      m = mn;
      float p[4][4];
      float r = 0.f;
#pragma unroll
      for (int nt = 0; nt < 4; ++nt)
#pragma unroll
        for (int i = 0; i < 4; ++i) {
          p[nt][i] = __expf((st[nt][i] - mn) * 0.125f);
          r += p[nt][i];
        }
      r += __shfl_xor(r, 16, 64);
      r += __shfl_xor(r, 32, 64);
      l = l * alpha + r;
#pragma unroll
      for (int dt = 0; dt < 4; ++dt)
#pragma unroll
        for (int i = 0; i < 4; ++i) O[dt][i] *= alpha;

#pragma unroll
      for (int nt = 0; nt < 4; ++nt) {
        uint2 o = { pk_bf16(p[nt][0], p[nt][1]), pk_bf16(p[nt][2], p[nt][3]) };
        *(uint2*)&Ps[w][l15 * 72 + nt * 16 + quad * 4] = o;
      }
      s8v bp0 = *(const s8v*)&Ps[w][l15 * 72 + quad * 8];
      s8v bp1 = *(const s8v*)&Ps[w][l15 * 72 + 32 + quad * 8];
#pragma unroll
      for (int dt = 0; dt < 4; ++dt) {
        const short* p2 = &VTs[(dt * 16 + l15) * 72 + quad * 8];
        s8v av0 = *(const s8v*)p2;
        s8v av1 = *(const s8v*)(p2 + 32);
        O[dt] = __builtin_amdgcn_mfma_f32_16x16x32_bf16(av0, bp0, O[dt], 0, 0, 0);
        O[dt] = __builtin_amdgcn_mfma_f32_16x16x32_bf16(av1, bp1, O[dt], 0, 0, 0);
      }
    }

    __syncthreads();
    if (kt < ktmax) {
      *(uint4*)&Ks[prow * 72 + pd8] = pk;
      *(uint4*)&VTs[prow * 72 + pd8] = pv;
    }
    __syncthreads();
  }

  const float inv = 1.f / l;
  const size_t row = qrow0 + w * 16 + l15;
#pragma unroll
  for (int dt = 0; dt < 4; ++dt) {
    uint2 o = { pk_bf16(O[dt][0] * inv, O[dt][1] * inv),
                pk_bf16(O[dt][2] * inv, O[dt][3] * inv) };
    *(uint2*)&AOb[row * kD + dh + dt * 16 + quad * 4] = o;
  }
}

// ---------------------------------------------------------------------------
// WO-GEMM: out[t][d] = sum_e AO[t][e] * wob[d][e].  All-bf16, BK=64,
// global_load_lds swizzled staging for both operands.
// ---------------------------------------------------------------------------
__global__ __launch_bounds__(256) void wo_gemm(const u16* __restrict__ AOb,
                                               const u16* __restrict__ wob,
                                               float* __restrict__ out) {
  __shared__ short As[128 * 64];
  __shared__ short Bs[128 * 64];
  const int tid = threadIdx.x;
  const int lane = tid & 63, wid = tid >> 6;
  const int wm = wid & 1, wn = wid >> 1;
  const int quad = lane >> 4, l15 = lane & 15;
  const int dT = blockIdx.x * 128;
  const int tok0 = blockIdx.y * 128;

  f32x4 acc[4][4];
#pragma unroll
  for (int mt = 0; mt < 4; ++mt)
#pragma unroll
    for (int nt = 0; nt < 4; ++nt) acc[mt][nt] = {0.f, 0.f, 0.f, 0.f};

#pragma unroll 1
  for (int e0 = 0; e0 < kD; e0 += 64) {
    __syncthreads();
#pragma unroll
    for (int e = 0; e < 4; ++e) {                 // A: AO, DMA swizzled
      int flat = tid + e * 256;
      int r = flat >> 3, u = (flat & 7) ^ (r & 7);
      gl_lds16(&AOb[(size_t)(tok0 + r) * kD + e0 + u * 8], &As[flat * 8]);
    }
#pragma unroll
    for (int e = 0; e < 4; ++e) {                 // B: wob, DMA swizzled
      int flat = tid + e * 256;
      int r = flat >> 3, u = (flat & 7) ^ (r & 7);
      gl_lds16(&wob[(size_t)(dT + r) * kD + e0 + u * 8], &Bs[flat * 8]);
    }
    __syncthreads();
    s8v a0[4], a1[4], b0[4], b1[4];
#pragma unroll
    for (int mt = 0; mt < 4; ++mt) {
      int r = wm * 64 + mt * 16 + l15;
      a0[mt] = *(const s8v*)&As[r * 64 + ((quad) ^ (r & 7)) * 8];
      a1[mt] = *(const s8v*)&As[r * 64 + ((4 + quad) ^ (r & 7)) * 8];
    }
#pragma unroll
    for (int nt = 0; nt < 4; ++nt) {
      int r = wn * 64 + nt * 16 + l15;
      b0[nt] = *(const s8v*)&Bs[r * 64 + ((quad) ^ (r & 7)) * 8];
      b1[nt] = *(const s8v*)&Bs[r * 64 + ((4 + quad) ^ (r & 7)) * 8];
    }
#pragma unroll
    for (int mt = 0; mt < 4; ++mt)
#pragma unroll
      for (int nt = 0; nt < 4; ++nt) {
        acc[mt][nt] = __builtin_amdgcn_mfma_f32_16x16x32_bf16(
            a0[mt], b0[nt], acc[mt][nt], 0, 0, 0);
        acc[mt][nt] = __builtin_amdgcn_mfma_f32_16x16x32_bf16(
            a1[mt], b1[nt], acc[mt][nt], 0, 0, 0);
      }
  }
#pragma unroll
  for (int mt = 0; mt < 4; ++mt)
#pragma unroll
    for (int nt = 0; nt < 4; ++nt) {
      int col = dT + wn * 64 + nt * 16 + l15;
      int rbase = tok0 + wm * 64 + mt * 16 + quad * 4;
#pragma unroll
      for (int i = 0; i < 4; ++i)
        out[(size_t)(rbase + i) * kD + col] = acc[mt][nt][i];
    }
}

// ---------------------------------------------------------------------------
extern "C" void kernel_launch(void* const* d_in, const int* in_sizes, int n_in,
                              void* d_out, int out_size, void* d_ws, size_t ws_size,
                              hipStream_t stream) {
  const float* x     = (const float*)d_in[0];
  const float* fqk_w = (const float*)d_in[1];
  const float* fv_w  = (const float*)d_in[2];
  const float* wq    = (const float*)d_in[3];
  const float* wk    = (const float*)d_in[4];
  const float* wv    = (const float*)d_in[5];
  const float* f_neu = (const float*)d_in[6];
  const float* r_neu = (const float*)d_in[7];
  const float* WO    = (const float*)d_in[8];
  float* out = (float*)d_out;

  // ws layout (100 MB, lifetime-overlapped):
  //  [0,8)    FT (dead after g_gemm)
  //  [8,16)   RT (dead after qkv_gemm) -> wob [8,10) (conv_wo after qkv)
  //  [16,80)  G  (dead after reduce_h) -> Qb [16,32), Kb [32,48), VTg [48,64),
  //                                       AOb [64,80)
  //  [80,84)  h_qk, h_v
  //  [84,100) xb (bf16 x)
  char* ws = (char*)d_ws;
  u16*   FT   = (u16*)  (ws);
  u16*   RT   = (u16*)  (ws + ((size_t)8u  << 20));
  u16*   wob  = (u16*)  (ws + ((size_t)8u  << 20));
  u16*   G    = (u16*)  (ws + ((size_t)16u << 20));
  float* h_qk = (float*)(ws + ((size_t)80u << 20));
  float* h_v  = (float*)(ws + ((size_t)82u << 20));
  u16*   Qb   = (u16*)  (ws + ((size_t)16u << 20));
  u16*   Kb   = (u16*)  (ws + ((size_t)32u << 20));
  u16*   VTg  = (u16*)  (ws + ((size_t)48u << 20));
  u16*   AOb  = (u16*)  (ws + ((size_t)64u << 20));
  u16*   xb   = (u16*)  (ws + ((size_t)84u << 20));

  hipLaunchKernelGGL(conv_x, dim3(4096), dim3(256), 0, stream, x, xb);
  hipLaunchKernelGGL(t1_kernel, dim3(8, 64), dim3(256), 0, stream, f_neu, FT);
  hipLaunchKernelGGL(t2_kernel, dim3(8, 64), dim3(256), 0, stream, r_neu, RT);
  hipLaunchKernelGGL(g_gemm, dim3(32, 64), dim3(256), 0, stream, xb, FT, G);
  hipLaunchKernelGGL(reduce_h, dim3(512), dim3(256), 0, stream,
                     G, fqk_w, fv_w, h_qk, h_v);
  hipLaunchKernelGGL(qkv_gemm, dim3(8, 64, 3), dim3(256), 0, stream,
                     h_qk, h_v, wq, wk, wv, RT, Qb, Kb, VTg);
  hipLaunchKernelGGL(conv_wo, dim3(512), dim3(256), 0, stream, WO, wob);
  hipLaunchKernelGGL(attn_mfma, dim3(16, 16, 4), dim3(512), 0, stream,
                     Qb, Kb, VTg, AOb);
  hipLaunchKernelGGL(wo_gemm, dim3(8, 64), dim3(256), 0, stream,
                     AOb, wob, out);
}